// Round 1
// baseline (890.769 us; speedup 1.0000x reference)
//
#include <hip/hip_runtime.h>

#define N_NODES 50000
#define N_EDGES 800000
#define N_PAIRS 8192
#define N_SLOTS (2 * N_PAIRS)

// Sinkhorn constants (log2 domain):
//   val2 = g~ + Crow2, where g~ = g/(eps*ln2), Crow2 = -(C/eps + ln32)*log2e
#define INV_EPS   20.0f
#define LOG2E_F   1.4426950408889634f
#define LN2_F     0.6931471805599453f
#define LN32_F    3.4657359027997265f
#define EPS_F     0.05f
#define N_ITER    50

// ---------------------------------------------------------------- mark needed
__global__ void k_mark(const int* __restrict__ pairs, int* __restrict__ flags) {
    int t = blockIdx.x * 256 + threadIdx.x;
    if (t < N_SLOTS) flags[pairs[t]] = 1;
}

// ------------------------------------------------- degree + raw-x aggregation
// agg_h = (sum_src x[src]) @ W by linearity, so aggregate 128-d x rows.
// 32 lanes per edge (float4 each = 128 floats). Only edges whose dst is needed.
__global__ __launch_bounds__(256) void k_deg_agg(
        const int* __restrict__ eidx, const float* __restrict__ x,
        const int* __restrict__ flags, float* __restrict__ deg,
        float* __restrict__ agg) {
    int t = blockIdx.x * 256 + threadIdx.x;
    int e = t >> 5;            // exact grid: no tail check needed
    int lane = t & 31;
    int dst = eidx[N_EDGES + e];
    if (!flags[dst]) return;
    int src = eidx[e];
    if (lane == 0) unsafeAtomicAdd(&deg[dst], 1.0f);
    float4 xv = ((const float4*)(x + (size_t)src * 128))[lane];
    float* ap = agg + (size_t)dst * 128 + lane * 4;
    unsafeAtomicAdd(ap + 0, xv.x);
    unsafeAtomicAdd(ap + 1, xv.y);
    unsafeAtomicAdd(ap + 2, xv.z);
    unsafeAtomicAdd(ap + 3, xv.w);
}

// --------------------------------------------------------------- fused GEMM+relu
// Z[s] = relu( (x[node] + agg[node]/max(deg,1)) @ W ), 16 slots x 256 cols / block.
__global__ __launch_bounds__(256) void k_gemm(
        const int* __restrict__ pairs, const float* __restrict__ x,
        const float* __restrict__ agg, const float* __restrict__ deg,
        const float* __restrict__ W, float* __restrict__ Z) {
    __shared__ __align__(16) float Us[16 * 128];
    int sbase = blockIdx.x * 16;
    int t = threadIdx.x;

    // stage u = x[node] + agg[node]*rdeg : 2048 floats, 2 float4 per thread
    #pragma unroll
    for (int h = 0; h < 2; ++h) {
        int fi = (t + h * 256) * 4;       // float index in tile
        int r  = fi >> 7;                 // tile row 0..15
        int d  = fi & 127;
        int node = pairs[sbase + r];
        float rdeg = 1.0f / fmaxf(deg[node], 1.0f);
        float4 xv = *(const float4*)(x   + (size_t)node * 128 + d);
        float4 av = *(const float4*)(agg + (size_t)node * 128 + d);
        float4 u;
        u.x = fmaf(av.x, rdeg, xv.x);
        u.y = fmaf(av.y, rdeg, xv.y);
        u.z = fmaf(av.z, rdeg, xv.z);
        u.w = fmaf(av.w, rdeg, xv.w);
        *(float4*)(Us + fi) = u;
    }
    __syncthreads();

    int jq = t & 63;   // column quad: cols 4*jq..4*jq+3
    int rq = t >> 6;   // row quad group: rows 4*rq..4*rq+3
    float acc[4][4] = {};
    const float4* Wv = (const float4*)W;   // W[128][256]

    for (int k4 = 0; k4 < 32; ++k4) {
        float4 wv[4];
        #pragma unroll
        for (int i = 0; i < 4; ++i) wv[i] = Wv[(size_t)(k4 * 4 + i) * 64 + jq];
        #pragma unroll
        for (int r = 0; r < 4; ++r) {
            float4 uv = *(const float4*)(Us + (rq * 4 + r) * 128 + k4 * 4);
            float uk0 = uv.x, uk1 = uv.y, uk2 = uv.z, uk3 = uv.w;
            acc[r][0] = fmaf(uk0, wv[0].x, acc[r][0]);
            acc[r][1] = fmaf(uk0, wv[0].y, acc[r][1]);
            acc[r][2] = fmaf(uk0, wv[0].z, acc[r][2]);
            acc[r][3] = fmaf(uk0, wv[0].w, acc[r][3]);
            acc[r][0] = fmaf(uk1, wv[1].x, acc[r][0]);
            acc[r][1] = fmaf(uk1, wv[1].y, acc[r][1]);
            acc[r][2] = fmaf(uk1, wv[1].z, acc[r][2]);
            acc[r][3] = fmaf(uk1, wv[1].w, acc[r][3]);
            acc[r][0] = fmaf(uk2, wv[2].x, acc[r][0]);
            acc[r][1] = fmaf(uk2, wv[2].y, acc[r][1]);
            acc[r][2] = fmaf(uk2, wv[2].z, acc[r][2]);
            acc[r][3] = fmaf(uk2, wv[2].w, acc[r][3]);
            acc[r][0] = fmaf(uk3, wv[3].x, acc[r][0]);
            acc[r][1] = fmaf(uk3, wv[3].y, acc[r][1]);
            acc[r][2] = fmaf(uk3, wv[3].z, acc[r][2]);
            acc[r][3] = fmaf(uk3, wv[3].w, acc[r][3]);
        }
    }

    #pragma unroll
    for (int r = 0; r < 4; ++r) {
        float4 o;
        o.x = fmaxf(acc[r][0], 0.0f);
        o.y = fmaxf(acc[r][1], 0.0f);
        o.z = fmaxf(acc[r][2], 0.0f);
        o.w = fmaxf(acc[r][3], 0.0f);
        *(float4*)(Z + (size_t)(sbase + rq * 4 + r) * 256 + jq * 4) = o;
    }
}

// ------------------------------------------------------------------- sinkhorn
// One wave per OT. Lane layouts:
//   row:  i = lane&31, jh = lane>>5 -> holds Crow2[t] = C2[i][16*jh+t]
//   col:  j = lane&31, ih = lane>>5 -> holds Ccol2[t] = C2[16*ih+t][j]
// where C2 = -(C*inv_eps + ln32)*log2e. f~/g~ exchanged via per-wave LDS.
__global__ __launch_bounds__(256) void k_sinkhorn(
        const float* __restrict__ Z, float* __restrict__ dist) {
    __shared__ __align__(16) float sX[4][256];
    __shared__ __align__(16) float sY[4][256];
    __shared__ __align__(16) float sf[4][32];
    __shared__ __align__(16) float sg[4][32];

    int w = threadIdx.x >> 6;
    int lane = threadIdx.x & 63;
    int task = blockIdx.x * 4 + w;            // grid is exact: 6144*4 = 24576
    int b = task / 3;
    int kind = task - 3 * b;                  // 0: (a,b)  1: (a,a)  2: (b,b)
    int sx = (kind == 2) ? (N_PAIRS + b) : b;
    int sy = (kind == 1) ? b : (N_PAIRS + b);

    // stage point clouds (32 pts x 8 dims = 256 floats each)
    *(float4*)(&sX[w][lane * 4]) = ((const float4*)(Z + (size_t)sx * 256))[lane];
    *(float4*)(&sY[w][lane * 4]) = ((const float4*)(Z + (size_t)sy * 256))[lane];
    if (lane < 32) sg[w][lane] = 0.0f;
    __syncthreads();

    const float CSCALE = -INV_EPS * LOG2E_F;
    const float CBIAS  = -LN32_F * LOG2E_F;

    int i_r = lane & 31, jh = lane >> 5;
    int j_c = lane & 31, ih = lane >> 5;

    float Crow2[16], Ccol2[16];
    {
        float4 xa = *(const float4*)(&sX[w][i_r * 8]);
        float4 xb = *(const float4*)(&sX[w][i_r * 8 + 4]);
        #pragma unroll
        for (int t = 0; t < 16; ++t) {
            int j = jh * 16 + t;
            float4 ya = *(const float4*)(&sY[w][j * 8]);
            float4 yb = *(const float4*)(&sY[w][j * 8 + 4]);
            float d2 = 1e-12f, dx;
            dx = xa.x - ya.x; d2 = fmaf(dx, dx, d2);
            dx = xa.y - ya.y; d2 = fmaf(dx, dx, d2);
            dx = xa.z - ya.z; d2 = fmaf(dx, dx, d2);
            dx = xa.w - ya.w; d2 = fmaf(dx, dx, d2);
            dx = xb.x - yb.x; d2 = fmaf(dx, dx, d2);
            dx = xb.y - yb.y; d2 = fmaf(dx, dx, d2);
            dx = xb.z - yb.z; d2 = fmaf(dx, dx, d2);
            dx = xb.w - yb.w; d2 = fmaf(dx, dx, d2);
            Crow2[t] = fmaf(__builtin_amdgcn_sqrtf(d2), CSCALE, CBIAS);
        }
        float4 ya = *(const float4*)(&sY[w][j_c * 8]);
        float4 yb = *(const float4*)(&sY[w][j_c * 8 + 4]);
        #pragma unroll
        for (int t = 0; t < 16; ++t) {
            int i = ih * 16 + t;
            float4 qa = *(const float4*)(&sX[w][i * 8]);
            float4 qb = *(const float4*)(&sX[w][i * 8 + 4]);
            float d2 = 1e-12f, dx;
            dx = qa.x - ya.x; d2 = fmaf(dx, dx, d2);
            dx = qa.y - ya.y; d2 = fmaf(dx, dx, d2);
            dx = qa.z - ya.z; d2 = fmaf(dx, dx, d2);
            dx = qa.w - ya.w; d2 = fmaf(dx, dx, d2);
            dx = qb.x - yb.x; d2 = fmaf(dx, dx, d2);
            dx = qb.y - yb.y; d2 = fmaf(dx, dx, d2);
            dx = qb.z - yb.z; d2 = fmaf(dx, dx, d2);
            dx = qb.w - yb.w; d2 = fmaf(dx, dx, d2);
            Ccol2[t] = fmaf(__builtin_amdgcn_sqrtf(d2), CSCALE, CBIAS);
        }
    }

    float ft = 0.0f, gt = 0.0f;
    for (int it = 0; it < N_ITER; ++it) {
        // ---- f-step: reduce over j for each row i
        {
            const float4* gp = (const float4*)(&sg[w][jh * 16]);
            float4 g0 = gp[0], g1 = gp[1], g2 = gp[2], g3 = gp[3];
            float gv[16] = {g0.x, g0.y, g0.z, g0.w, g1.x, g1.y, g1.z, g1.w,
                            g2.x, g2.y, g2.z, g2.w, g3.x, g3.y, g3.z, g3.w};
            float val[16], m = -1e30f;
            #pragma unroll
            for (int t = 0; t < 16; ++t) {
                val[t] = gv[t] + Crow2[t];
                m = fmaxf(m, val[t]);
            }
            m = fmaxf(m, __shfl_xor(m, 32));
            float s = 0.0f;
            #pragma unroll
            for (int t = 0; t < 16; ++t) s += __builtin_amdgcn_exp2f(val[t] - m);
            s += __shfl_xor(s, 32);
            ft = -(m + __builtin_amdgcn_logf(s));   // v_log_f32 = log2
        }
        if (lane < 32) sf[w][lane] = ft;
        __syncthreads();
        // ---- g-step: reduce over i for each col j
        {
            const float4* fp = (const float4*)(&sf[w][ih * 16]);
            float4 f0 = fp[0], f1 = fp[1], f2 = fp[2], f3 = fp[3];
            float fv[16] = {f0.x, f0.y, f0.z, f0.w, f1.x, f1.y, f1.z, f1.w,
                            f2.x, f2.y, f2.z, f2.w, f3.x, f3.y, f3.z, f3.w};
            float val[16], m = -1e30f;
            #pragma unroll
            for (int t = 0; t < 16; ++t) {
                val[t] = fv[t] + Ccol2[t];
                m = fmaxf(m, val[t]);
            }
            m = fmaxf(m, __shfl_xor(m, 32));
            float s = 0.0f;
            #pragma unroll
            for (int t = 0; t < 16; ++t) s += __builtin_amdgcn_exp2f(val[t] - m);
            s += __shfl_xor(s, 32);
            gt = -(m + __builtin_amdgcn_logf(s));
        }
        if (lane < 32) sg[w][lane] = gt;
        __syncthreads();
    }

    // dual cost = mean(f)+mean(g) = eps*ln2*(sum f~ + sum g~)/32; wave sum
    // counts each value twice (both halves) -> /64.
    float v = ft + gt;
    #pragma unroll
    for (int off = 32; off > 0; off >>= 1) v += __shfl_xor(v, off);
    if (lane == 0) {
        float cost = v * (EPS_F * LN2_F / 64.0f);
        float wgt = (kind == 0) ? 1.0f : -0.5f;
        unsafeAtomicAdd(&dist[b], wgt * cost);
    }
}

// ------------------------------------------------------------------ finalize
__global__ void k_finalize(const float* __restrict__ dist,
                           const float* __restrict__ gd, float* __restrict__ out) {
    __shared__ float red[256];
    float s = 0.0f;
    for (int i = threadIdx.x; i < N_PAIRS; i += 256) {
        float g = gd[i];
        s += fabsf(dist[i] - g) / g;
    }
    red[threadIdx.x] = s;
    __syncthreads();
    for (int o = 128; o > 0; o >>= 1) {
        if (threadIdx.x < o) red[threadIdx.x] += red[threadIdx.x + o];
        __syncthreads();
    }
    if (threadIdx.x == 0) out[0] = red[0] * (1.0f / N_PAIRS);
}

// -------------------------------------------------------------------- launch
extern "C" void kernel_launch(void* const* d_in, const int* in_sizes, int n_in,
                              void* d_out, int out_size, void* d_ws, size_t ws_size,
                              hipStream_t stream) {
    const float* x    = (const float*)d_in[0];   // [50000,128]
    const float* W    = (const float*)d_in[1];   // [128,256]
    const int*   eidx = (const int*)d_in[2];     // [2,800000]
    const int*   pair = (const int*)d_in[3];     // [2,8192] flattened = 16384 slots
    const float* gd   = (const float*)d_in[4];   // [8192]

    char* ws = (char*)d_ws;
    size_t off = 0;
    float* agg   = (float*)(ws + off); off += (size_t)N_NODES * 128 * 4; // 25.6 MB
    float* deg   = (float*)(ws + off); off += (size_t)N_NODES * 4;
    int*   flags = (int*)  (ws + off); off += (size_t)N_NODES * 4;
    float* dist  = (float*)(ws + off); off += (size_t)N_PAIRS * 4;
    size_t zero_bytes = off;                     // agg+deg+flags+dist contiguous
    float* Z     = (float*)(ws + off); off += (size_t)N_SLOTS * 256 * 4; // 16.8 MB

    hipMemsetAsync(d_ws, 0, zero_bytes, stream);
    k_mark<<<(N_SLOTS + 255) / 256, 256, 0, stream>>>(pair, flags);
    k_deg_agg<<<(N_EDGES * 32) / 256, 256, 0, stream>>>(eidx, x, flags, deg, agg);
    k_gemm<<<N_SLOTS / 16, 256, 0, stream>>>(pair, x, agg, deg, W, Z);
    k_sinkhorn<<<(3 * N_PAIRS) / 4, 256, 0, stream>>>(Z, dist);
    k_finalize<<<1, 256, 0, stream>>>(dist, gd, (float*)d_out);
}

// Round 2
// 639.606 us; speedup vs baseline: 1.3927x; 1.3927x over previous
//
#include <hip/hip_runtime.h>

#define N_NODES 50000
#define N_EDGES 800000
#define N_PAIRS 8192
#define N_SLOTS (2 * N_PAIRS)

// Sinkhorn constants (log2 domain):
//   val2 = g~ + Crow2, where g~ = g/(eps*ln2), Crow2 = -(C/eps + ln32)*log2e
#define INV_EPS   20.0f
#define LOG2E_F   1.4426950408889634f
#define LN2_F     0.6931471805599453f
#define LN32_F    3.4657359027997265f
#define EPS_F     0.05f
#define N_ITER    50

// ---------------------------------------------------------------- mark needed
__global__ void k_mark(const int* __restrict__ pairs, int* __restrict__ flags) {
    int t = blockIdx.x * 256 + threadIdx.x;
    if (t < N_SLOTS) flags[pairs[t]] = 1;
}

// ------------------------------------------------------------- CSR: count
__global__ __launch_bounds__(256) void k_count(
        const int* __restrict__ eidx, const int* __restrict__ flags,
        int* __restrict__ cnt) {
    int t = blockIdx.x * 256 + threadIdx.x;   // exact grid: 800000/256 = 3125
    int dst = eidx[N_EDGES + t];
    if (flags[dst]) atomicAdd(&cnt[dst], 1);
}

// ------------------------------------------------------------- CSR: scan
// Single block, 1024 threads, 49 nodes per thread (49*1024 >= 50000).
__global__ __launch_bounds__(1024) void k_scan(
        const int* __restrict__ cnt, int* __restrict__ offs,
        int* __restrict__ cursor) {
    __shared__ int part[1024];
    int t = threadIdx.x;
    int base = t * 49;
    int s = 0;
    #pragma unroll 7
    for (int i = 0; i < 49; ++i) {
        int idx = base + i;
        s += (idx < N_NODES) ? cnt[idx] : 0;
    }
    part[t] = s;
    __syncthreads();
    for (int o = 1; o < 1024; o <<= 1) {
        int v = (t >= o) ? part[t - o] : 0;
        __syncthreads();
        part[t] += v;
        __syncthreads();
    }
    int run = (t > 0) ? part[t - 1] : 0;
    for (int i = 0; i < 49; ++i) {
        int idx = base + i;
        if (idx < N_NODES) {
            offs[idx] = run;
            cursor[idx] = run;
            run += cnt[idx];
        }
    }
}

// ------------------------------------------------------------- CSR: scatter
__global__ __launch_bounds__(256) void k_scatter(
        const int* __restrict__ eidx, const int* __restrict__ flags,
        int* __restrict__ cursor, int* __restrict__ bucket) {
    int t = blockIdx.x * 256 + threadIdx.x;   // exact grid
    int dst = eidx[N_EDGES + t];
    if (!flags[dst]) return;
    int pos = atomicAdd(&cursor[dst], 1);
    bucket[pos] = eidx[t];
}

// ---------------------------------------------------- gather + fuse u = x+agg/deg
// One wave per node; lane l holds floats 2l, 2l+1 of the 128-d row.
__global__ __launch_bounds__(256) void k_gather(
        const int* __restrict__ flags, const int* __restrict__ cnt,
        const int* __restrict__ offs, const int* __restrict__ bucket,
        const float* __restrict__ x, float* __restrict__ u) {
    int wid = (blockIdx.x * 256 + threadIdx.x) >> 6;
    int lane = threadIdx.x & 63;
    if (wid >= N_NODES) return;
    int node = wid;
    if (!flags[node]) return;
    int n   = __builtin_amdgcn_readfirstlane(cnt[node]);
    int off = __builtin_amdgcn_readfirstlane(offs[node]);
    float ax = 0.0f, ay = 0.0f;
    int k = 0;
    for (; k + 4 <= n; k += 4) {
        int s0 = bucket[off + k];
        int s1 = bucket[off + k + 1];
        int s2 = bucket[off + k + 2];
        int s3 = bucket[off + k + 3];
        float2 v0 = *(const float2*)(x + (size_t)s0 * 128 + lane * 2);
        float2 v1 = *(const float2*)(x + (size_t)s1 * 128 + lane * 2);
        float2 v2 = *(const float2*)(x + (size_t)s2 * 128 + lane * 2);
        float2 v3 = *(const float2*)(x + (size_t)s3 * 128 + lane * 2);
        ax += (v0.x + v1.x) + (v2.x + v3.x);
        ay += (v0.y + v1.y) + (v2.y + v3.y);
    }
    for (; k < n; ++k) {
        int s0 = bucket[off + k];
        float2 v0 = *(const float2*)(x + (size_t)s0 * 128 + lane * 2);
        ax += v0.x;
        ay += v0.y;
    }
    float rdeg = 1.0f / fmaxf((float)n, 1.0f);
    float2 xv = *(const float2*)(x + (size_t)node * 128 + lane * 2);
    float2 o;
    o.x = fmaf(ax, rdeg, xv.x);
    o.y = fmaf(ay, rdeg, xv.y);
    *(float2*)(u + (size_t)node * 128 + lane * 2) = o;
}

// --------------------------------------------------------------- fused GEMM+relu
// Z[s] = relu( u[node] @ W ), 16 slots x 256 cols per block.
__global__ __launch_bounds__(256) void k_gemm(
        const int* __restrict__ pairs, const float* __restrict__ u,
        const float* __restrict__ W, float* __restrict__ Z) {
    __shared__ __align__(16) float Us[16 * 128];
    int sbase = blockIdx.x * 16;
    int t = threadIdx.x;

    #pragma unroll
    for (int h = 0; h < 2; ++h) {
        int fi = (t + h * 256) * 4;       // float index in tile
        int r  = fi >> 7;                 // tile row 0..15
        int d  = fi & 127;
        int node = pairs[sbase + r];
        *(float4*)(Us + fi) = *(const float4*)(u + (size_t)node * 128 + d);
    }
    __syncthreads();

    int jq = t & 63;   // column quad: cols 4*jq..4*jq+3
    int rq = t >> 6;   // row quad group: rows 4*rq..4*rq+3
    float acc[4][4] = {};
    const float4* Wv = (const float4*)W;   // W[128][256]

    for (int k4 = 0; k4 < 32; ++k4) {
        float4 wv[4];
        #pragma unroll
        for (int i = 0; i < 4; ++i) wv[i] = Wv[(size_t)(k4 * 4 + i) * 64 + jq];
        #pragma unroll
        for (int r = 0; r < 4; ++r) {
            float4 uv = *(const float4*)(Us + (rq * 4 + r) * 128 + k4 * 4);
            float uk0 = uv.x, uk1 = uv.y, uk2 = uv.z, uk3 = uv.w;
            acc[r][0] = fmaf(uk0, wv[0].x, acc[r][0]);
            acc[r][1] = fmaf(uk0, wv[0].y, acc[r][1]);
            acc[r][2] = fmaf(uk0, wv[0].z, acc[r][2]);
            acc[r][3] = fmaf(uk0, wv[0].w, acc[r][3]);
            acc[r][0] = fmaf(uk1, wv[1].x, acc[r][0]);
            acc[r][1] = fmaf(uk1, wv[1].y, acc[r][1]);
            acc[r][2] = fmaf(uk1, wv[1].z, acc[r][2]);
            acc[r][3] = fmaf(uk1, wv[1].w, acc[r][3]);
            acc[r][0] = fmaf(uk2, wv[2].x, acc[r][0]);
            acc[r][1] = fmaf(uk2, wv[2].y, acc[r][1]);
            acc[r][2] = fmaf(uk2, wv[2].z, acc[r][2]);
            acc[r][3] = fmaf(uk2, wv[2].w, acc[r][3]);
            acc[r][0] = fmaf(uk3, wv[3].x, acc[r][0]);
            acc[r][1] = fmaf(uk3, wv[3].y, acc[r][1]);
            acc[r][2] = fmaf(uk3, wv[3].z, acc[r][2]);
            acc[r][3] = fmaf(uk3, wv[3].w, acc[r][3]);
        }
    }

    #pragma unroll
    for (int r = 0; r < 4; ++r) {
        float4 o;
        o.x = fmaxf(acc[r][0], 0.0f);
        o.y = fmaxf(acc[r][1], 0.0f);
        o.z = fmaxf(acc[r][2], 0.0f);
        o.w = fmaxf(acc[r][3], 0.0f);
        *(float4*)(Z + (size_t)(sbase + rq * 4 + r) * 256 + jq * 4) = o;
    }
}

// ------------------------------------------------------------------- sinkhorn
// One wave per OT. Lane layouts:
//   row:  i = lane&31, jh = lane>>5 -> holds Crow2[t] = C2[i][16*jh+t]
//   col:  j = lane&31, ih = lane>>5 -> holds Ccol2[t] = C2[16*ih+t][j]
// where C2 = -(C*inv_eps + ln32)*log2e. f~/g~ exchanged via per-wave LDS.
__global__ __launch_bounds__(256) void k_sinkhorn(
        const float* __restrict__ Z, float* __restrict__ dist) {
    __shared__ __align__(16) float sX[4][256];
    __shared__ __align__(16) float sY[4][256];
    __shared__ __align__(16) float sf[4][32];
    __shared__ __align__(16) float sg[4][32];

    int w = threadIdx.x >> 6;
    int lane = threadIdx.x & 63;
    int task = blockIdx.x * 4 + w;            // grid is exact: 6144*4 = 24576
    int b = task / 3;
    int kind = task - 3 * b;                  // 0: (a,b)  1: (a,a)  2: (b,b)
    int sx = (kind == 2) ? (N_PAIRS + b) : b;
    int sy = (kind == 1) ? b : (N_PAIRS + b);

    // stage point clouds (32 pts x 8 dims = 256 floats each)
    *(float4*)(&sX[w][lane * 4]) = ((const float4*)(Z + (size_t)sx * 256))[lane];
    *(float4*)(&sY[w][lane * 4]) = ((const float4*)(Z + (size_t)sy * 256))[lane];
    if (lane < 32) sg[w][lane] = 0.0f;
    __syncthreads();

    const float CSCALE = -INV_EPS * LOG2E_F;
    const float CBIAS  = -LN32_F * LOG2E_F;

    int i_r = lane & 31, jh = lane >> 5;
    int j_c = lane & 31, ih = lane >> 5;

    float Crow2[16], Ccol2[16];
    {
        float4 xa = *(const float4*)(&sX[w][i_r * 8]);
        float4 xb = *(const float4*)(&sX[w][i_r * 8 + 4]);
        #pragma unroll
        for (int t = 0; t < 16; ++t) {
            int j = jh * 16 + t;
            float4 ya = *(const float4*)(&sY[w][j * 8]);
            float4 yb = *(const float4*)(&sY[w][j * 8 + 4]);
            float d2 = 1e-12f, dx;
            dx = xa.x - ya.x; d2 = fmaf(dx, dx, d2);
            dx = xa.y - ya.y; d2 = fmaf(dx, dx, d2);
            dx = xa.z - ya.z; d2 = fmaf(dx, dx, d2);
            dx = xa.w - ya.w; d2 = fmaf(dx, dx, d2);
            dx = xb.x - yb.x; d2 = fmaf(dx, dx, d2);
            dx = xb.y - yb.y; d2 = fmaf(dx, dx, d2);
            dx = xb.z - yb.z; d2 = fmaf(dx, dx, d2);
            dx = xb.w - yb.w; d2 = fmaf(dx, dx, d2);
            Crow2[t] = fmaf(__builtin_amdgcn_sqrtf(d2), CSCALE, CBIAS);
        }
        float4 ya = *(const float4*)(&sY[w][j_c * 8]);
        float4 yb = *(const float4*)(&sY[w][j_c * 8 + 4]);
        #pragma unroll
        for (int t = 0; t < 16; ++t) {
            int i = ih * 16 + t;
            float4 qa = *(const float4*)(&sX[w][i * 8]);
            float4 qb = *(const float4*)(&sX[w][i * 8 + 4]);
            float d2 = 1e-12f, dx;
            dx = qa.x - ya.x; d2 = fmaf(dx, dx, d2);
            dx = qa.y - ya.y; d2 = fmaf(dx, dx, d2);
            dx = qa.z - ya.z; d2 = fmaf(dx, dx, d2);
            dx = qa.w - ya.w; d2 = fmaf(dx, dx, d2);
            dx = qb.x - yb.x; d2 = fmaf(dx, dx, d2);
            dx = qb.y - yb.y; d2 = fmaf(dx, dx, d2);
            dx = qb.z - yb.z; d2 = fmaf(dx, dx, d2);
            dx = qb.w - yb.w; d2 = fmaf(dx, dx, d2);
            Ccol2[t] = fmaf(__builtin_amdgcn_sqrtf(d2), CSCALE, CBIAS);
        }
    }

    float ft = 0.0f, gt = 0.0f;
    for (int it = 0; it < N_ITER; ++it) {
        // ---- f-step: reduce over j for each row i
        {
            const float4* gp = (const float4*)(&sg[w][jh * 16]);
            float4 g0 = gp[0], g1 = gp[1], g2 = gp[2], g3 = gp[3];
            float gv[16] = {g0.x, g0.y, g0.z, g0.w, g1.x, g1.y, g1.z, g1.w,
                            g2.x, g2.y, g2.z, g2.w, g3.x, g3.y, g3.z, g3.w};
            float val[16], m = -1e30f;
            #pragma unroll
            for (int t = 0; t < 16; ++t) {
                val[t] = gv[t] + Crow2[t];
                m = fmaxf(m, val[t]);
            }
            m = fmaxf(m, __shfl_xor(m, 32));
            float s = 0.0f;
            #pragma unroll
            for (int t = 0; t < 16; ++t) s += __builtin_amdgcn_exp2f(val[t] - m);
            s += __shfl_xor(s, 32);
            ft = -(m + __builtin_amdgcn_logf(s));   // v_log_f32 = log2
        }
        if (lane < 32) sf[w][lane] = ft;
        __syncthreads();
        // ---- g-step: reduce over i for each col j
        {
            const float4* fp = (const float4*)(&sf[w][ih * 16]);
            float4 f0 = fp[0], f1 = fp[1], f2 = fp[2], f3 = fp[3];
            float fv[16] = {f0.x, f0.y, f0.z, f0.w, f1.x, f1.y, f1.z, f1.w,
                            f2.x, f2.y, f2.z, f2.w, f3.x, f3.y, f3.z, f3.w};
            float val[16], m = -1e30f;
            #pragma unroll
            for (int t = 0; t < 16; ++t) {
                val[t] = fv[t] + Ccol2[t];
                m = fmaxf(m, val[t]);
            }
            m = fmaxf(m, __shfl_xor(m, 32));
            float s = 0.0f;
            #pragma unroll
            for (int t = 0; t < 16; ++t) s += __builtin_amdgcn_exp2f(val[t] - m);
            s += __shfl_xor(s, 32);
            gt = -(m + __builtin_amdgcn_logf(s));
        }
        if (lane < 32) sg[w][lane] = gt;
        __syncthreads();
    }

    // dual cost = mean(f)+mean(g) = eps*ln2*(sum f~ + sum g~)/32; wave sum
    // counts each value twice (both halves) -> /64.
    float v = ft + gt;
    #pragma unroll
    for (int off = 32; off > 0; off >>= 1) v += __shfl_xor(v, off);
    if (lane == 0) {
        float cost = v * (EPS_F * LN2_F / 64.0f);
        float wgt = (kind == 0) ? 1.0f : -0.5f;
        unsafeAtomicAdd(&dist[b], wgt * cost);
    }
}

// ------------------------------------------------------------------ finalize
__global__ void k_finalize(const float* __restrict__ dist,
                           const float* __restrict__ gd, float* __restrict__ out) {
    __shared__ float red[256];
    float s = 0.0f;
    for (int i = threadIdx.x; i < N_PAIRS; i += 256) {
        float g = gd[i];
        s += fabsf(dist[i] - g) / g;
    }
    red[threadIdx.x] = s;
    __syncthreads();
    for (int o = 128; o > 0; o >>= 1) {
        if (threadIdx.x < o) red[threadIdx.x] += red[threadIdx.x + o];
        __syncthreads();
    }
    if (threadIdx.x == 0) out[0] = red[0] * (1.0f / N_PAIRS);
}

// -------------------------------------------------------------------- launch
extern "C" void kernel_launch(void* const* d_in, const int* in_sizes, int n_in,
                              void* d_out, int out_size, void* d_ws, size_t ws_size,
                              hipStream_t stream) {
    const float* x    = (const float*)d_in[0];   // [50000,128]
    const float* W    = (const float*)d_in[1];   // [128,256]
    const int*   eidx = (const int*)d_in[2];     // [2,800000]
    const int*   pair = (const int*)d_in[3];     // [2,8192] flat = 16384 slots
    const float* gd   = (const float*)d_in[4];   // [8192]

    char* ws = (char*)d_ws;
    size_t off = 0;
    float* u      = (float*)(ws + off); off += (size_t)N_NODES * 128 * 4;  // 25.6 MB
    size_t zoff = off;
    int*   cnt    = (int*)  (ws + off); off += (size_t)N_NODES * 4;
    int*   flags  = (int*)  (ws + off); off += (size_t)N_NODES * 4;
    float* dist   = (float*)(ws + off); off += (size_t)N_PAIRS * 4;
    size_t zero_bytes = off - zoff;              // cnt+flags+dist contiguous
    int*   offs   = (int*)  (ws + off); off += (size_t)N_NODES * 4;
    int*   cursor = (int*)  (ws + off); off += (size_t)N_NODES * 4;
    // bucket and Z share storage: bucket dead before Z is written.
    int*   bucket = (int*)  (ws + off);
    float* Z      = (float*)(ws + off); off += (size_t)N_SLOTS * 256 * 4;  // 16.8 MB

    hipMemsetAsync(ws + zoff, 0, zero_bytes, stream);
    k_mark   <<<(N_SLOTS + 255) / 256, 256, 0, stream>>>(pair, flags);
    k_count  <<<N_EDGES / 256, 256, 0, stream>>>(eidx, flags, cnt);
    k_scan   <<<1, 1024, 0, stream>>>(cnt, offs, cursor);
    k_scatter<<<N_EDGES / 256, 256, 0, stream>>>(eidx, flags, cursor, bucket);
    k_gather <<<(N_NODES * 64 + 255) / 256, 256, 0, stream>>>(flags, cnt, offs, bucket, x, u);
    k_gemm   <<<N_SLOTS / 16, 256, 0, stream>>>(pair, u, W, Z);
    k_sinkhorn<<<(3 * N_PAIRS) / 4, 256, 0, stream>>>(Z, dist);
    k_finalize<<<1, 256, 0, stream>>>(dist, gd, (float*)d_out);
}

// Round 3
// 439.487 us; speedup vs baseline: 2.0268x; 1.4553x over previous
//
#include <hip/hip_runtime.h>

#define N_NODES 50000
#define N_EDGES 800000
#define N_PAIRS 8192
#define N_SLOTS (2 * N_PAIRS)

// Sinkhorn constants (log2 domain):
//   val2 = g~ + Crow2, where g~ = g/(eps*ln2), Crow2 = -(C/eps + ln32)*log2e
#define INV_EPS   20.0f
#define LOG2E_F   1.4426950408889634f
#define LN2_F     0.6931471805599453f
#define LN32_F    3.4657359027997265f
#define EPS_F     0.05f

// ---------------------------------------------------------------- mark needed
__global__ void k_mark(const int* __restrict__ pairs, int* __restrict__ flags) {
    int t = blockIdx.x * 256 + threadIdx.x;
    if (t < N_SLOTS) flags[pairs[t]] = 1;
}

// ------------------------------------------------------------- CSR: count
__global__ __launch_bounds__(256) void k_count(
        const int* __restrict__ eidx, const int* __restrict__ flags,
        int* __restrict__ cnt) {
    int t = blockIdx.x * 256 + threadIdx.x;   // exact grid: 800000/256 = 3125
    int dst = eidx[N_EDGES + t];
    if (flags[dst]) atomicAdd(&cnt[dst], 1);
}

// ------------------------------------------------------------- CSR: scan
// Single block, 1024 threads, 49 nodes per thread (49*1024 >= 50000).
__global__ __launch_bounds__(1024) void k_scan(
        const int* __restrict__ cnt, int* __restrict__ offs,
        int* __restrict__ cursor) {
    __shared__ int part[1024];
    int t = threadIdx.x;
    int base = t * 49;
    int s = 0;
    #pragma unroll 7
    for (int i = 0; i < 49; ++i) {
        int idx = base + i;
        s += (idx < N_NODES) ? cnt[idx] : 0;
    }
    part[t] = s;
    __syncthreads();
    for (int o = 1; o < 1024; o <<= 1) {
        int v = (t >= o) ? part[t - o] : 0;
        __syncthreads();
        part[t] += v;
        __syncthreads();
    }
    int run = (t > 0) ? part[t - 1] : 0;
    for (int i = 0; i < 49; ++i) {
        int idx = base + i;
        if (idx < N_NODES) {
            offs[idx] = run;
            cursor[idx] = run;
            run += cnt[idx];
        }
    }
}

// ------------------------------------------------------------- CSR: scatter
__global__ __launch_bounds__(256) void k_scatter(
        const int* __restrict__ eidx, const int* __restrict__ flags,
        int* __restrict__ cursor, int* __restrict__ bucket) {
    int t = blockIdx.x * 256 + threadIdx.x;   // exact grid
    int dst = eidx[N_EDGES + t];
    if (!flags[dst]) return;
    int pos = atomicAdd(&cursor[dst], 1);
    bucket[pos] = eidx[t];
}

// ---------------------------------------------------- gather + fuse u = x+agg/deg
// One wave per node; lane l holds floats 2l, 2l+1 of the 128-d row.
__global__ __launch_bounds__(256) void k_gather(
        const int* __restrict__ flags, const int* __restrict__ cnt,
        const int* __restrict__ offs, const int* __restrict__ bucket,
        const float* __restrict__ x, float* __restrict__ u) {
    int wid = (blockIdx.x * 256 + threadIdx.x) >> 6;
    int lane = threadIdx.x & 63;
    if (wid >= N_NODES) return;
    int node = wid;
    if (!flags[node]) return;
    int n   = __builtin_amdgcn_readfirstlane(cnt[node]);
    int off = __builtin_amdgcn_readfirstlane(offs[node]);
    float ax = 0.0f, ay = 0.0f;
    int k = 0;
    for (; k + 4 <= n; k += 4) {
        int s0 = bucket[off + k];
        int s1 = bucket[off + k + 1];
        int s2 = bucket[off + k + 2];
        int s3 = bucket[off + k + 3];
        float2 v0 = *(const float2*)(x + (size_t)s0 * 128 + lane * 2);
        float2 v1 = *(const float2*)(x + (size_t)s1 * 128 + lane * 2);
        float2 v2 = *(const float2*)(x + (size_t)s2 * 128 + lane * 2);
        float2 v3 = *(const float2*)(x + (size_t)s3 * 128 + lane * 2);
        ax += (v0.x + v1.x) + (v2.x + v3.x);
        ay += (v0.y + v1.y) + (v2.y + v3.y);
    }
    for (; k < n; ++k) {
        int s0 = bucket[off + k];
        float2 v0 = *(const float2*)(x + (size_t)s0 * 128 + lane * 2);
        ax += v0.x;
        ay += v0.y;
    }
    float rdeg = 1.0f / fmaxf((float)n, 1.0f);
    float2 xv = *(const float2*)(x + (size_t)node * 128 + lane * 2);
    float2 o;
    o.x = fmaf(ax, rdeg, xv.x);
    o.y = fmaf(ay, rdeg, xv.y);
    *(float2*)(u + (size_t)node * 128 + lane * 2) = o;
}

// --------------------------------------------------------------- fused GEMM+relu
// Z[s] = relu( u[node] @ W ), 16 slots x 256 cols per block.
__global__ __launch_bounds__(256) void k_gemm(
        const int* __restrict__ pairs, const float* __restrict__ u,
        const float* __restrict__ W, float* __restrict__ Z) {
    __shared__ __align__(16) float Us[16 * 128];
    int sbase = blockIdx.x * 16;
    int t = threadIdx.x;

    #pragma unroll
    for (int h = 0; h < 2; ++h) {
        int fi = (t + h * 256) * 4;       // float index in tile
        int r  = fi >> 7;                 // tile row 0..15
        int d  = fi & 127;
        int node = pairs[sbase + r];
        *(float4*)(Us + fi) = *(const float4*)(u + (size_t)node * 128 + d);
    }
    __syncthreads();

    int jq = t & 63;   // column quad: cols 4*jq..4*jq+3
    int rq = t >> 6;   // row quad group: rows 4*rq..4*rq+3
    float acc[4][4] = {};
    const float4* Wv = (const float4*)W;   // W[128][256]

    for (int k4 = 0; k4 < 32; ++k4) {
        float4 wv[4];
        #pragma unroll
        for (int i = 0; i < 4; ++i) wv[i] = Wv[(size_t)(k4 * 4 + i) * 64 + jq];
        #pragma unroll
        for (int r = 0; r < 4; ++r) {
            float4 uv = *(const float4*)(Us + (rq * 4 + r) * 128 + k4 * 4);
            float uk0 = uv.x, uk1 = uv.y, uk2 = uv.z, uk3 = uv.w;
            acc[r][0] = fmaf(uk0, wv[0].x, acc[r][0]);
            acc[r][1] = fmaf(uk0, wv[0].y, acc[r][1]);
            acc[r][2] = fmaf(uk0, wv[0].z, acc[r][2]);
            acc[r][3] = fmaf(uk0, wv[0].w, acc[r][3]);
            acc[r][0] = fmaf(uk1, wv[1].x, acc[r][0]);
            acc[r][1] = fmaf(uk1, wv[1].y, acc[r][1]);
            acc[r][2] = fmaf(uk1, wv[1].z, acc[r][2]);
            acc[r][3] = fmaf(uk1, wv[1].w, acc[r][3]);
            acc[r][0] = fmaf(uk2, wv[2].x, acc[r][0]);
            acc[r][1] = fmaf(uk2, wv[2].y, acc[r][1]);
            acc[r][2] = fmaf(uk2, wv[2].z, acc[r][2]);
            acc[r][3] = fmaf(uk2, wv[2].w, acc[r][3]);
            acc[r][0] = fmaf(uk3, wv[3].x, acc[r][0]);
            acc[r][1] = fmaf(uk3, wv[3].y, acc[r][1]);
            acc[r][2] = fmaf(uk3, wv[3].z, acc[r][2]);
            acc[r][3] = fmaf(uk3, wv[3].w, acc[r][3]);
        }
    }

    #pragma unroll
    for (int r = 0; r < 4; ++r) {
        float4 o;
        o.x = fmaxf(acc[r][0], 0.0f);
        o.y = fmaxf(acc[r][1], 0.0f);
        o.z = fmaxf(acc[r][2], 0.0f);
        o.w = fmaxf(acc[r][3], 0.0f);
        *(float4*)(Z + (size_t)(sbase + rq * 4 + r) * 256 + jq * 4) = o;
    }
}

// ------------------------------------------------------------------- sinkhorn
// One wave per OT; each wave uses only its own LDS slice -> NO __syncthreads
// anywhere (wave-synchronous; compiler orders aliasing ds_write/ds_read).
// Phase A: 2 log-domain iterations (as before).
// Phase B: absorbed exp-domain iterations u=1/(K v), v=1/(K^T u) with
//   K = exp2(phi_i + gamma_j + C2_ij) held in 32 VGPRs; re-absorb every 6
//   iters to keep u,v in fp32 range. Mathematically identical sequence.
__global__ __launch_bounds__(256) void k_sinkhorn(
        const float* __restrict__ Z, float* __restrict__ dist) {
    __shared__ __align__(16) float sX[4][256];
    __shared__ __align__(16) float sY[4][256];
    __shared__ __align__(16) float sf[4][32];
    __shared__ __align__(16) float sg[4][32];
    __shared__ __align__(16) float su[4][32];
    __shared__ __align__(16) float sv[4][32];

    int w = threadIdx.x >> 6;
    int lane = threadIdx.x & 63;
    int task = blockIdx.x * 4 + w;            // grid is exact: 6144*4 = 24576
    int b = task / 3;
    int kind = task - 3 * b;                  // 0: (a,b)  1: (a,a)  2: (b,b)
    int sx = (kind == 2) ? (N_PAIRS + b) : b;
    int sy = (kind == 1) ? b : (N_PAIRS + b);

    // stage point clouds (32 pts x 8 dims = 256 floats each)
    *(float4*)(&sX[w][lane * 4]) = ((const float4*)(Z + (size_t)sx * 256))[lane];
    *(float4*)(&sY[w][lane * 4]) = ((const float4*)(Z + (size_t)sy * 256))[lane];
    if (lane < 32) sg[w][lane] = 0.0f;

    const float CSCALE = -INV_EPS * LOG2E_F;
    const float CBIAS  = -LN32_F * LOG2E_F;

    int i_r = lane & 31, jh = lane >> 5;
    int j_c = lane & 31, ih = lane >> 5;

    float Crow2[16], Ccol2[16];
    {
        float4 xa = *(const float4*)(&sX[w][i_r * 8]);
        float4 xb = *(const float4*)(&sX[w][i_r * 8 + 4]);
        #pragma unroll
        for (int t = 0; t < 16; ++t) {
            int j = jh * 16 + t;
            float4 ya = *(const float4*)(&sY[w][j * 8]);
            float4 yb = *(const float4*)(&sY[w][j * 8 + 4]);
            float d2 = 1e-12f, dx;
            dx = xa.x - ya.x; d2 = fmaf(dx, dx, d2);
            dx = xa.y - ya.y; d2 = fmaf(dx, dx, d2);
            dx = xa.z - ya.z; d2 = fmaf(dx, dx, d2);
            dx = xa.w - ya.w; d2 = fmaf(dx, dx, d2);
            dx = xb.x - yb.x; d2 = fmaf(dx, dx, d2);
            dx = xb.y - yb.y; d2 = fmaf(dx, dx, d2);
            dx = xb.z - yb.z; d2 = fmaf(dx, dx, d2);
            dx = xb.w - yb.w; d2 = fmaf(dx, dx, d2);
            Crow2[t] = fmaf(__builtin_amdgcn_sqrtf(d2), CSCALE, CBIAS);
        }
        float4 ya = *(const float4*)(&sY[w][j_c * 8]);
        float4 yb = *(const float4*)(&sY[w][j_c * 8 + 4]);
        #pragma unroll
        for (int t = 0; t < 16; ++t) {
            int i = ih * 16 + t;
            float4 qa = *(const float4*)(&sX[w][i * 8]);
            float4 qb = *(const float4*)(&sX[w][i * 8 + 4]);
            float d2 = 1e-12f, dx;
            dx = qa.x - ya.x; d2 = fmaf(dx, dx, d2);
            dx = qa.y - ya.y; d2 = fmaf(dx, dx, d2);
            dx = qa.z - ya.z; d2 = fmaf(dx, dx, d2);
            dx = qa.w - ya.w; d2 = fmaf(dx, dx, d2);
            dx = qb.x - yb.x; d2 = fmaf(dx, dx, d2);
            dx = qb.y - yb.y; d2 = fmaf(dx, dx, d2);
            dx = qb.z - yb.z; d2 = fmaf(dx, dx, d2);
            dx = qb.w - yb.w; d2 = fmaf(dx, dx, d2);
            Ccol2[t] = fmaf(__builtin_amdgcn_sqrtf(d2), CSCALE, CBIAS);
        }
    }

    float ft = 0.0f, gt = 0.0f;

    // ---- Phase A: 2 log-domain iterations
    #pragma unroll 1
    for (int it = 0; it < 2; ++it) {
        {
            const float4* gp = (const float4*)(&sg[w][jh * 16]);
            float4 g0 = gp[0], g1 = gp[1], g2 = gp[2], g3 = gp[3];
            float gv[16] = {g0.x, g0.y, g0.z, g0.w, g1.x, g1.y, g1.z, g1.w,
                            g2.x, g2.y, g2.z, g2.w, g3.x, g3.y, g3.z, g3.w};
            float val[16], m = -1e30f;
            #pragma unroll
            for (int t = 0; t < 16; ++t) {
                val[t] = gv[t] + Crow2[t];
                m = fmaxf(m, val[t]);
            }
            m = fmaxf(m, __shfl_xor(m, 32));
            float s = 0.0f;
            #pragma unroll
            for (int t = 0; t < 16; ++t) s += __builtin_amdgcn_exp2f(val[t] - m);
            s += __shfl_xor(s, 32);
            ft = -(m + __builtin_amdgcn_logf(s));   // v_log_f32 = log2
        }
        if (lane < 32) sf[w][lane] = ft;
        {
            const float4* fp = (const float4*)(&sf[w][ih * 16]);
            float4 f0 = fp[0], f1 = fp[1], f2 = fp[2], f3 = fp[3];
            float fv[16] = {f0.x, f0.y, f0.z, f0.w, f1.x, f1.y, f1.z, f1.w,
                            f2.x, f2.y, f2.z, f2.w, f3.x, f3.y, f3.z, f3.w};
            float val[16], m = -1e30f;
            #pragma unroll
            for (int t = 0; t < 16; ++t) {
                val[t] = fv[t] + Ccol2[t];
                m = fmaxf(m, val[t]);
            }
            m = fmaxf(m, __shfl_xor(m, 32));
            float s = 0.0f;
            #pragma unroll
            for (int t = 0; t < 16; ++t) s += __builtin_amdgcn_exp2f(val[t] - m);
            s += __shfl_xor(s, 32);
            gt = -(m + __builtin_amdgcn_logf(s));
        }
        if (lane < 32) sg[w][lane] = gt;
    }

    // ---- Phase B: absorbed exp-domain
    float KR[16], KC[16];
    float ureg = 1.0f, vreg = 1.0f;

    auto absorb = [&]() {
        const float4* gp = (const float4*)(&sg[w][jh * 16]);
        float4 g0 = gp[0], g1 = gp[1], g2 = gp[2], g3 = gp[3];
        float gv[16] = {g0.x, g0.y, g0.z, g0.w, g1.x, g1.y, g1.z, g1.w,
                        g2.x, g2.y, g2.z, g2.w, g3.x, g3.y, g3.z, g3.w};
        #pragma unroll
        for (int t = 0; t < 16; ++t)
            KR[t] = __builtin_amdgcn_exp2f(ft + gv[t] + Crow2[t]);
        const float4* fp = (const float4*)(&sf[w][ih * 16]);
        float4 f0 = fp[0], f1 = fp[1], f2 = fp[2], f3 = fp[3];
        float fv[16] = {f0.x, f0.y, f0.z, f0.w, f1.x, f1.y, f1.z, f1.w,
                        f2.x, f2.y, f2.z, f2.w, f3.x, f3.y, f3.z, f3.w};
        #pragma unroll
        for (int t = 0; t < 16; ++t)
            KC[t] = __builtin_amdgcn_exp2f(gt + fv[t] + Ccol2[t]);
        if (lane < 32) sv[w][lane] = 1.0f;
        ureg = 1.0f;
        vreg = 1.0f;
    };

    absorb();
    #pragma unroll 1
    for (int blk = 0; blk < 8; ++blk) {       // 8 blocks x 6 = 48 exp iters
        #pragma unroll
        for (int s6 = 0; s6 < 6; ++s6) {
            // f-step: u = 1/(KR . v)
            {
                const float4* vp = (const float4*)(&sv[w][jh * 16]);
                float4 a0 = vp[0], a1 = vp[1], a2 = vp[2], a3 = vp[3];
                float vv[16] = {a0.x, a0.y, a0.z, a0.w, a1.x, a1.y, a1.z, a1.w,
                                a2.x, a2.y, a2.z, a2.w, a3.x, a3.y, a3.z, a3.w};
                float S = 0.0f;
                #pragma unroll
                for (int t = 0; t < 16; ++t) S = fmaf(KR[t], vv[t], S);
                S += __shfl_xor(S, 32);
                ureg = __builtin_amdgcn_rcpf(S);
            }
            if (lane < 32) su[w][lane] = ureg;
            // g-step: v = 1/(KC . u)
            {
                const float4* up = (const float4*)(&su[w][ih * 16]);
                float4 a0 = up[0], a1 = up[1], a2 = up[2], a3 = up[3];
                float uu[16] = {a0.x, a0.y, a0.z, a0.w, a1.x, a1.y, a1.z, a1.w,
                                a2.x, a2.y, a2.z, a2.w, a3.x, a3.y, a3.z, a3.w};
                float T = 0.0f;
                #pragma unroll
                for (int t = 0; t < 16; ++t) T = fmaf(KC[t], uu[t], T);
                T += __shfl_xor(T, 32);
                vreg = __builtin_amdgcn_rcpf(T);
            }
            if (lane < 32) sv[w][lane] = vreg;
        }
        if (blk < 7) {
            ft += __builtin_amdgcn_logf(ureg);
            gt += __builtin_amdgcn_logf(vreg);
            if (lane < 32) { sf[w][lane] = ft; sg[w][lane] = gt; }
            absorb();
        }
    }
    ft += __builtin_amdgcn_logf(ureg);
    gt += __builtin_amdgcn_logf(vreg);

    // dual cost = eps*ln2*(sum f~ + sum g~)/32; wave sum double-counts -> /64.
    float v = ft + gt;
    #pragma unroll
    for (int off = 32; off > 0; off >>= 1) v += __shfl_xor(v, off);
    if (lane == 0) {
        float cost = v * (EPS_F * LN2_F / 64.0f);
        float wgt = (kind == 0) ? 1.0f : -0.5f;
        unsafeAtomicAdd(&dist[b], wgt * cost);
    }
}

// ------------------------------------------------------------------ finalize
__global__ void k_finalize(const float* __restrict__ dist,
                           const float* __restrict__ gd, float* __restrict__ out) {
    __shared__ float red[256];
    float s = 0.0f;
    for (int i = threadIdx.x; i < N_PAIRS; i += 256) {
        float g = gd[i];
        s += fabsf(dist[i] - g) / g;
    }
    red[threadIdx.x] = s;
    __syncthreads();
    for (int o = 128; o > 0; o >>= 1) {
        if (threadIdx.x < o) red[threadIdx.x] += red[threadIdx.x + o];
        __syncthreads();
    }
    if (threadIdx.x == 0) out[0] = red[0] * (1.0f / N_PAIRS);
}

// -------------------------------------------------------------------- launch
extern "C" void kernel_launch(void* const* d_in, const int* in_sizes, int n_in,
                              void* d_out, int out_size, void* d_ws, size_t ws_size,
                              hipStream_t stream) {
    const float* x    = (const float*)d_in[0];   // [50000,128]
    const float* W    = (const float*)d_in[1];   // [128,256]
    const int*   eidx = (const int*)d_in[2];     // [2,800000]
    const int*   pair = (const int*)d_in[3];     // [2,8192] flat = 16384 slots
    const float* gd   = (const float*)d_in[4];   // [8192]

    char* ws = (char*)d_ws;
    size_t off = 0;
    float* u      = (float*)(ws + off); off += (size_t)N_NODES * 128 * 4;  // 25.6 MB
    size_t zoff = off;
    int*   cnt    = (int*)  (ws + off); off += (size_t)N_NODES * 4;
    int*   flags  = (int*)  (ws + off); off += (size_t)N_NODES * 4;
    float* dist   = (float*)(ws + off); off += (size_t)N_PAIRS * 4;
    size_t zero_bytes = off - zoff;              // cnt+flags+dist contiguous
    int*   offs   = (int*)  (ws + off); off += (size_t)N_NODES * 4;
    int*   cursor = (int*)  (ws + off); off += (size_t)N_NODES * 4;
    // bucket and Z share storage: bucket dead before Z is written.
    int*   bucket = (int*)  (ws + off);
    float* Z      = (float*)(ws + off); off += (size_t)N_SLOTS * 256 * 4;  // 16.8 MB

    hipMemsetAsync(ws + zoff, 0, zero_bytes, stream);
    k_mark   <<<(N_SLOTS + 255) / 256, 256, 0, stream>>>(pair, flags);
    k_count  <<<N_EDGES / 256, 256, 0, stream>>>(eidx, flags, cnt);
    k_scan   <<<1, 1024, 0, stream>>>(cnt, offs, cursor);
    k_scatter<<<N_EDGES / 256, 256, 0, stream>>>(eidx, flags, cursor, bucket);
    k_gather <<<(N_NODES * 64 + 255) / 256, 256, 0, stream>>>(flags, cnt, offs, bucket, x, u);
    k_gemm   <<<N_SLOTS / 16, 256, 0, stream>>>(pair, u, W, Z);
    k_sinkhorn<<<(3 * N_PAIRS) / 4, 256, 0, stream>>>(Z, dist);
    k_finalize<<<1, 256, 0, stream>>>(dist, gd, (float*)d_out);
}

// Round 4
// 304.183 us; speedup vs baseline: 2.9284x; 1.4448x over previous
//
#include <hip/hip_runtime.h>

#define N_NODES 50000
#define N_EDGES 800000
#define N_PAIRS 8192
#define N_SLOTS (2 * N_PAIRS)
#define CAP     64          // per-node bucket capacity; P(deg>63)~5e-19

// Sinkhorn constants (log2 domain):
//   val2 = g~ + Crow2, where g~ = g/(eps*ln2), Crow2 = -(C/eps + ln32)*log2e
#define INV_EPS   20.0f
#define LOG2E_F   1.4426950408889634f
#define LN2_F     0.6931471805599453f
#define LN32_F    3.4657359027997265f
#define EPS_F     0.05f

// ---------------------------------------------------------------- mark needed
__global__ void k_mark(const int* __restrict__ pairs, int* __restrict__ flags) {
    int t = blockIdx.x * 256 + threadIdx.x;
    if (t < N_SLOTS) flags[pairs[t]] = 1;
}

// ---------------------------------------- scatter into fixed-cap buckets
// cnt[dst] counts FULL in-degree (for the deg normalization); bucket holds
// up to CAP src indices. Only flagged dst nodes participate.
__global__ __launch_bounds__(256) void k_scatter(
        const int* __restrict__ eidx, const int* __restrict__ flags,
        int* __restrict__ cnt, int* __restrict__ bucket) {
    int t = blockIdx.x * 256 + threadIdx.x;   // exact grid: 800000/256
    int dst = eidx[N_EDGES + t];
    if (!flags[dst]) return;
    int pos = atomicAdd(&cnt[dst], 1);
    if (pos < CAP) bucket[dst * CAP + pos] = eidx[t];
}

// ------------------------------------ fused gather + GEMM + relu
// Z[s] = relu( (x[node] + agg[node]/max(deg,1)) @ W ), 16 slots per block.
// Each of the 4 waves gathers 4 slots' neighbor sums straight into LDS.
__global__ __launch_bounds__(256) void k_gemm(
        const int* __restrict__ pairs, const float* __restrict__ x,
        const int* __restrict__ cnt, const int* __restrict__ bucket,
        const float* __restrict__ W, float* __restrict__ Z) {
    __shared__ __align__(16) float Us[16 * 128];
    int sbase = blockIdx.x * 16;
    int t = threadIdx.x;
    int wave = t >> 6, lane = t & 63;

    #pragma unroll
    for (int rr = 0; rr < 4; ++rr) {
        int r = wave * 4 + rr;
        int node = pairs[sbase + r];
        int n = cnt[node];
        int m = (n < CAP) ? n : CAP;
        const int* bk = bucket + node * CAP;
        float ax = 0.0f, ay = 0.0f;
        int k = 0;
        for (; k + 4 <= m; k += 4) {
            int s0 = bk[k], s1 = bk[k + 1], s2 = bk[k + 2], s3 = bk[k + 3];
            float2 v0 = *(const float2*)(x + (size_t)s0 * 128 + lane * 2);
            float2 v1 = *(const float2*)(x + (size_t)s1 * 128 + lane * 2);
            float2 v2 = *(const float2*)(x + (size_t)s2 * 128 + lane * 2);
            float2 v3 = *(const float2*)(x + (size_t)s3 * 128 + lane * 2);
            ax += (v0.x + v1.x) + (v2.x + v3.x);
            ay += (v0.y + v1.y) + (v2.y + v3.y);
        }
        for (; k < m; ++k) {
            int s0 = bk[k];
            float2 v0 = *(const float2*)(x + (size_t)s0 * 128 + lane * 2);
            ax += v0.x;
            ay += v0.y;
        }
        float rdeg = 1.0f / fmaxf((float)n, 1.0f);
        float2 xv = *(const float2*)(x + (size_t)node * 128 + lane * 2);
        float2 o;
        o.x = fmaf(ax, rdeg, xv.x);
        o.y = fmaf(ay, rdeg, xv.y);
        *(float2*)(Us + r * 128 + lane * 2) = o;
    }
    __syncthreads();

    int jq = t & 63;   // column quad: cols 4*jq..4*jq+3
    int rq = t >> 6;   // row quad group: rows 4*rq..4*rq+3
    float acc[4][4] = {};
    const float4* Wv = (const float4*)W;   // W[128][256]

    for (int k4 = 0; k4 < 32; ++k4) {
        float4 wv[4];
        #pragma unroll
        for (int i = 0; i < 4; ++i) wv[i] = Wv[(size_t)(k4 * 4 + i) * 64 + jq];
        #pragma unroll
        for (int r = 0; r < 4; ++r) {
            float4 uv = *(const float4*)(Us + (rq * 4 + r) * 128 + k4 * 4);
            float uk0 = uv.x, uk1 = uv.y, uk2 = uv.z, uk3 = uv.w;
            acc[r][0] = fmaf(uk0, wv[0].x, acc[r][0]);
            acc[r][1] = fmaf(uk0, wv[0].y, acc[r][1]);
            acc[r][2] = fmaf(uk0, wv[0].z, acc[r][2]);
            acc[r][3] = fmaf(uk0, wv[0].w, acc[r][3]);
            acc[r][0] = fmaf(uk1, wv[1].x, acc[r][0]);
            acc[r][1] = fmaf(uk1, wv[1].y, acc[r][1]);
            acc[r][2] = fmaf(uk1, wv[1].z, acc[r][2]);
            acc[r][3] = fmaf(uk1, wv[1].w, acc[r][3]);
            acc[r][0] = fmaf(uk2, wv[2].x, acc[r][0]);
            acc[r][1] = fmaf(uk2, wv[2].y, acc[r][1]);
            acc[r][2] = fmaf(uk2, wv[2].z, acc[r][2]);
            acc[r][3] = fmaf(uk2, wv[2].w, acc[r][3]);
            acc[r][0] = fmaf(uk3, wv[3].x, acc[r][0]);
            acc[r][1] = fmaf(uk3, wv[3].y, acc[r][1]);
            acc[r][2] = fmaf(uk3, wv[3].z, acc[r][2]);
            acc[r][3] = fmaf(uk3, wv[3].w, acc[r][3]);
        }
    }

    #pragma unroll
    for (int r = 0; r < 4; ++r) {
        float4 o;
        o.x = fmaxf(acc[r][0], 0.0f);
        o.y = fmaxf(acc[r][1], 0.0f);
        o.z = fmaxf(acc[r][2], 0.0f);
        o.w = fmaxf(acc[r][3], 0.0f);
        *(float4*)(Z + (size_t)(sbase + rq * 4 + r) * 256 + jq * 4) = o;
    }
}

// ------------------------------------------------------------------- sinkhorn
// One wave per OT; each wave uses only its own LDS slice -> NO __syncthreads.
// Phase A: 2 log-domain iterations. Phase B: absorbed exp-domain iterations
// u=1/(K v), v=1/(K^T u) with K held in 32 VGPRs; re-absorb every 6 iters.
__global__ __launch_bounds__(256) void k_sinkhorn(
        const float* __restrict__ Z, float* __restrict__ dist) {
    __shared__ __align__(16) float sX[4][256];
    __shared__ __align__(16) float sY[4][256];
    __shared__ __align__(16) float sf[4][32];
    __shared__ __align__(16) float sg[4][32];
    __shared__ __align__(16) float su[4][32];
    __shared__ __align__(16) float sv[4][32];

    int w = threadIdx.x >> 6;
    int lane = threadIdx.x & 63;
    int task = blockIdx.x * 4 + w;            // grid is exact: 6144*4 = 24576
    int b = task / 3;
    int kind = task - 3 * b;                  // 0: (a,b)  1: (a,a)  2: (b,b)
    int sx = (kind == 2) ? (N_PAIRS + b) : b;
    int sy = (kind == 1) ? b : (N_PAIRS + b);

    *(float4*)(&sX[w][lane * 4]) = ((const float4*)(Z + (size_t)sx * 256))[lane];
    *(float4*)(&sY[w][lane * 4]) = ((const float4*)(Z + (size_t)sy * 256))[lane];
    if (lane < 32) sg[w][lane] = 0.0f;

    const float CSCALE = -INV_EPS * LOG2E_F;
    const float CBIAS  = -LN32_F * LOG2E_F;

    int i_r = lane & 31, jh = lane >> 5;
    int j_c = lane & 31, ih = lane >> 5;

    float Crow2[16], Ccol2[16];
    {
        float4 xa = *(const float4*)(&sX[w][i_r * 8]);
        float4 xb = *(const float4*)(&sX[w][i_r * 8 + 4]);
        #pragma unroll
        for (int t = 0; t < 16; ++t) {
            int j = jh * 16 + t;
            float4 ya = *(const float4*)(&sY[w][j * 8]);
            float4 yb = *(const float4*)(&sY[w][j * 8 + 4]);
            float d2 = 1e-12f, dx;
            dx = xa.x - ya.x; d2 = fmaf(dx, dx, d2);
            dx = xa.y - ya.y; d2 = fmaf(dx, dx, d2);
            dx = xa.z - ya.z; d2 = fmaf(dx, dx, d2);
            dx = xa.w - ya.w; d2 = fmaf(dx, dx, d2);
            dx = xb.x - yb.x; d2 = fmaf(dx, dx, d2);
            dx = xb.y - yb.y; d2 = fmaf(dx, dx, d2);
            dx = xb.z - yb.z; d2 = fmaf(dx, dx, d2);
            dx = xb.w - yb.w; d2 = fmaf(dx, dx, d2);
            Crow2[t] = fmaf(__builtin_amdgcn_sqrtf(d2), CSCALE, CBIAS);
        }
        float4 ya = *(const float4*)(&sY[w][j_c * 8]);
        float4 yb = *(const float4*)(&sY[w][j_c * 8 + 4]);
        #pragma unroll
        for (int t = 0; t < 16; ++t) {
            int i = ih * 16 + t;
            float4 qa = *(const float4*)(&sX[w][i * 8]);
            float4 qb = *(const float4*)(&sX[w][i * 8 + 4]);
            float d2 = 1e-12f, dx;
            dx = qa.x - ya.x; d2 = fmaf(dx, dx, d2);
            dx = qa.y - ya.y; d2 = fmaf(dx, dx, d2);
            dx = qa.z - ya.z; d2 = fmaf(dx, dx, d2);
            dx = qa.w - ya.w; d2 = fmaf(dx, dx, d2);
            dx = qb.x - yb.x; d2 = fmaf(dx, dx, d2);
            dx = qb.y - yb.y; d2 = fmaf(dx, dx, d2);
            dx = qb.z - yb.z; d2 = fmaf(dx, dx, d2);
            dx = qb.w - yb.w; d2 = fmaf(dx, dx, d2);
            Ccol2[t] = fmaf(__builtin_amdgcn_sqrtf(d2), CSCALE, CBIAS);
        }
    }

    float ft = 0.0f, gt = 0.0f;

    // ---- Phase A: 2 log-domain iterations
    #pragma unroll 1
    for (int it = 0; it < 2; ++it) {
        {
            const float4* gp = (const float4*)(&sg[w][jh * 16]);
            float4 g0 = gp[0], g1 = gp[1], g2 = gp[2], g3 = gp[3];
            float gv[16] = {g0.x, g0.y, g0.z, g0.w, g1.x, g1.y, g1.z, g1.w,
                            g2.x, g2.y, g2.z, g2.w, g3.x, g3.y, g3.z, g3.w};
            float val[16], m = -1e30f;
            #pragma unroll
            for (int t = 0; t < 16; ++t) {
                val[t] = gv[t] + Crow2[t];
                m = fmaxf(m, val[t]);
            }
            m = fmaxf(m, __shfl_xor(m, 32));
            float s = 0.0f;
            #pragma unroll
            for (int t = 0; t < 16; ++t) s += __builtin_amdgcn_exp2f(val[t] - m);
            s += __shfl_xor(s, 32);
            ft = -(m + __builtin_amdgcn_logf(s));   // v_log_f32 = log2
        }
        if (lane < 32) sf[w][lane] = ft;
        {
            const float4* fp = (const float4*)(&sf[w][ih * 16]);
            float4 f0 = fp[0], f1 = fp[1], f2 = fp[2], f3 = fp[3];
            float fv[16] = {f0.x, f0.y, f0.z, f0.w, f1.x, f1.y, f1.z, f1.w,
                            f2.x, f2.y, f2.z, f2.w, f3.x, f3.y, f3.z, f3.w};
            float val[16], m = -1e30f;
            #pragma unroll
            for (int t = 0; t < 16; ++t) {
                val[t] = fv[t] + Ccol2[t];
                m = fmaxf(m, val[t]);
            }
            m = fmaxf(m, __shfl_xor(m, 32));
            float s = 0.0f;
            #pragma unroll
            for (int t = 0; t < 16; ++t) s += __builtin_amdgcn_exp2f(val[t] - m);
            s += __shfl_xor(s, 32);
            gt = -(m + __builtin_amdgcn_logf(s));
        }
        if (lane < 32) sg[w][lane] = gt;
    }

    // ---- Phase B: absorbed exp-domain
    float KR[16], KC[16];
    float ureg = 1.0f, vreg = 1.0f;

    auto absorb = [&]() {
        const float4* gp = (const float4*)(&sg[w][jh * 16]);
        float4 g0 = gp[0], g1 = gp[1], g2 = gp[2], g3 = gp[3];
        float gv[16] = {g0.x, g0.y, g0.z, g0.w, g1.x, g1.y, g1.z, g1.w,
                        g2.x, g2.y, g2.z, g2.w, g3.x, g3.y, g3.z, g3.w};
        #pragma unroll
        for (int t = 0; t < 16; ++t)
            KR[t] = __builtin_amdgcn_exp2f(ft + gv[t] + Crow2[t]);
        const float4* fp = (const float4*)(&sf[w][ih * 16]);
        float4 f0 = fp[0], f1 = fp[1], f2 = fp[2], f3 = fp[3];
        float fv[16] = {f0.x, f0.y, f0.z, f0.w, f1.x, f1.y, f1.z, f1.w,
                        f2.x, f2.y, f2.z, f2.w, f3.x, f3.y, f3.z, f3.w};
        #pragma unroll
        for (int t = 0; t < 16; ++t)
            KC[t] = __builtin_amdgcn_exp2f(gt + fv[t] + Ccol2[t]);
        if (lane < 32) sv[w][lane] = 1.0f;
        ureg = 1.0f;
        vreg = 1.0f;
    };

    absorb();
    #pragma unroll 1
    for (int blk = 0; blk < 8; ++blk) {       // 8 blocks x 6 = 48 exp iters
        #pragma unroll
        for (int s6 = 0; s6 < 6; ++s6) {
            {
                const float4* vp = (const float4*)(&sv[w][jh * 16]);
                float4 a0 = vp[0], a1 = vp[1], a2 = vp[2], a3 = vp[3];
                float vv[16] = {a0.x, a0.y, a0.z, a0.w, a1.x, a1.y, a1.z, a1.w,
                                a2.x, a2.y, a2.z, a2.w, a3.x, a3.y, a3.z, a3.w};
                float S = 0.0f;
                #pragma unroll
                for (int t = 0; t < 16; ++t) S = fmaf(KR[t], vv[t], S);
                S += __shfl_xor(S, 32);
                ureg = __builtin_amdgcn_rcpf(S);
            }
            if (lane < 32) su[w][lane] = ureg;
            {
                const float4* up = (const float4*)(&su[w][ih * 16]);
                float4 a0 = up[0], a1 = up[1], a2 = up[2], a3 = up[3];
                float uu[16] = {a0.x, a0.y, a0.z, a0.w, a1.x, a1.y, a1.z, a1.w,
                                a2.x, a2.y, a2.z, a2.w, a3.x, a3.y, a3.z, a3.w};
                float T = 0.0f;
                #pragma unroll
                for (int t = 0; t < 16; ++t) T = fmaf(KC[t], uu[t], T);
                T += __shfl_xor(T, 32);
                vreg = __builtin_amdgcn_rcpf(T);
            }
            if (lane < 32) sv[w][lane] = vreg;
        }
        if (blk < 7) {
            ft += __builtin_amdgcn_logf(ureg);
            gt += __builtin_amdgcn_logf(vreg);
            if (lane < 32) { sf[w][lane] = ft; sg[w][lane] = gt; }
            absorb();
        }
    }
    ft += __builtin_amdgcn_logf(ureg);
    gt += __builtin_amdgcn_logf(vreg);

    // dual cost = eps*ln2*(sum f~ + sum g~)/32; wave sum double-counts -> /64.
    float v = ft + gt;
    #pragma unroll
    for (int off = 32; off > 0; off >>= 1) v += __shfl_xor(v, off);
    if (lane == 0) {
        float cost = v * (EPS_F * LN2_F / 64.0f);
        float wgt = (kind == 0) ? 1.0f : -0.5f;
        unsafeAtomicAdd(&dist[b], wgt * cost);
    }
}

// ------------------------------------------------------------------ finalize
__global__ void k_finalize(const float* __restrict__ dist,
                           const float* __restrict__ gd, float* __restrict__ out) {
    __shared__ float red[256];
    float s = 0.0f;
    for (int i = threadIdx.x; i < N_PAIRS; i += 256) {
        float g = gd[i];
        s += fabsf(dist[i] - g) / g;
    }
    red[threadIdx.x] = s;
    __syncthreads();
    for (int o = 128; o > 0; o >>= 1) {
        if (threadIdx.x < o) red[threadIdx.x] += red[threadIdx.x + o];
        __syncthreads();
    }
    if (threadIdx.x == 0) out[0] = red[0] * (1.0f / N_PAIRS);
}

// -------------------------------------------------------------------- launch
extern "C" void kernel_launch(void* const* d_in, const int* in_sizes, int n_in,
                              void* d_out, int out_size, void* d_ws, size_t ws_size,
                              hipStream_t stream) {
    const float* x    = (const float*)d_in[0];   // [50000,128]
    const float* W    = (const float*)d_in[1];   // [128,256]
    const int*   eidx = (const int*)d_in[2];     // [2,800000]
    const int*   pair = (const int*)d_in[3];     // [2,8192] flat = 16384 slots
    const float* gd   = (const float*)d_in[4];   // [8192]

    char* ws = (char*)d_ws;
    size_t off = 0;
    int*   cnt    = (int*)  (ws + off); off += (size_t)N_NODES * 4;
    int*   flags  = (int*)  (ws + off); off += (size_t)N_NODES * 4;
    float* dist   = (float*)(ws + off); off += (size_t)N_PAIRS * 4;
    size_t zero_bytes = off;                     // cnt+flags+dist contiguous
    int*   bucket = (int*)  (ws + off); off += (size_t)N_NODES * CAP * 4; // 12.8 MB
    float* Z      = (float*)(ws + off); off += (size_t)N_SLOTS * 256 * 4; // 16.8 MB

    hipMemsetAsync(d_ws, 0, zero_bytes, stream);
    k_mark    <<<(N_SLOTS + 255) / 256, 256, 0, stream>>>(pair, flags);
    k_scatter <<<N_EDGES / 256, 256, 0, stream>>>(eidx, flags, cnt, bucket);
    k_gemm    <<<N_SLOTS / 16, 256, 0, stream>>>(pair, x, cnt, bucket, W, Z);
    k_sinkhorn<<<(3 * N_PAIRS) / 4, 256, 0, stream>>>(Z, dist);
    k_finalize<<<1, 256, 0, stream>>>(dist, gd, (float*)d_out);
}

// Round 5
// 292.729 us; speedup vs baseline: 3.0430x; 1.0391x over previous
//
#include <hip/hip_runtime.h>

#define N_NODES 50000
#define N_EDGES 800000
#define N_PAIRS 8192
#define N_SLOTS (2 * N_PAIRS)
#define CAP     64          // per-node bucket capacity; P(deg>63)~5e-19

// Sinkhorn constants (log2 domain):
//   val2 = g~ + Crow2, where g~ = g/(eps*ln2), Crow2 = -(C/eps + ln32)*log2e
#define INV_EPS   20.0f
#define LOG2E_F   1.4426950408889634f
#define LN2_F     0.6931471805599453f
#define LN32_F    3.4657359027997265f
#define EPS_F     0.05f

typedef float f2 __attribute__((ext_vector_type(2)));

// ---------------------------------------------------------------- mark needed
__global__ void k_mark(const int* __restrict__ pairs, int* __restrict__ flags) {
    int t = blockIdx.x * 256 + threadIdx.x;
    if (t < N_SLOTS) flags[pairs[t]] = 1;
}

// ---------------------------------------- scatter into fixed-cap buckets
__global__ __launch_bounds__(256) void k_scatter(
        const int* __restrict__ eidx, const int* __restrict__ flags,
        int* __restrict__ cnt, int* __restrict__ bucket) {
    int t = blockIdx.x * 256 + threadIdx.x;   // exact grid: 800000/256
    int dst = eidx[N_EDGES + t];
    if (!flags[dst]) return;
    int pos = atomicAdd(&cnt[dst], 1);
    if (pos < CAP) bucket[dst * CAP + pos] = eidx[t];
}

// ------------------------------------ fused gather + GEMM + relu
__global__ __launch_bounds__(256) void k_gemm(
        const int* __restrict__ pairs, const float* __restrict__ x,
        const int* __restrict__ cnt, const int* __restrict__ bucket,
        const float* __restrict__ W, float* __restrict__ Z) {
    __shared__ __align__(16) float Us[16 * 128];
    int sbase = blockIdx.x * 16;
    int t = threadIdx.x;
    int wave = t >> 6, lane = t & 63;

    #pragma unroll
    for (int rr = 0; rr < 4; ++rr) {
        int r = wave * 4 + rr;
        int node = pairs[sbase + r];
        int n = cnt[node];
        int m = (n < CAP) ? n : CAP;
        const int* bk = bucket + node * CAP;
        float ax = 0.0f, ay = 0.0f;
        int k = 0;
        for (; k + 4 <= m; k += 4) {
            int s0 = bk[k], s1 = bk[k + 1], s2 = bk[k + 2], s3 = bk[k + 3];
            float2 v0 = *(const float2*)(x + (size_t)s0 * 128 + lane * 2);
            float2 v1 = *(const float2*)(x + (size_t)s1 * 128 + lane * 2);
            float2 v2 = *(const float2*)(x + (size_t)s2 * 128 + lane * 2);
            float2 v3 = *(const float2*)(x + (size_t)s3 * 128 + lane * 2);
            ax += (v0.x + v1.x) + (v2.x + v3.x);
            ay += (v0.y + v1.y) + (v2.y + v3.y);
        }
        for (; k < m; ++k) {
            int s0 = bk[k];
            float2 v0 = *(const float2*)(x + (size_t)s0 * 128 + lane * 2);
            ax += v0.x;
            ay += v0.y;
        }
        float rdeg = 1.0f / fmaxf((float)n, 1.0f);
        float2 xv = *(const float2*)(x + (size_t)node * 128 + lane * 2);
        float2 o;
        o.x = fmaf(ax, rdeg, xv.x);
        o.y = fmaf(ay, rdeg, xv.y);
        *(float2*)(Us + r * 128 + lane * 2) = o;
    }
    __syncthreads();

    int jq = t & 63;   // column quad: cols 4*jq..4*jq+3
    int rq = t >> 6;   // row quad group: rows 4*rq..4*rq+3
    float acc[4][4] = {};
    const float4* Wv = (const float4*)W;   // W[128][256]

    for (int k4 = 0; k4 < 32; ++k4) {
        float4 wv[4];
        #pragma unroll
        for (int i = 0; i < 4; ++i) wv[i] = Wv[(size_t)(k4 * 4 + i) * 64 + jq];
        #pragma unroll
        for (int r = 0; r < 4; ++r) {
            float4 uv = *(const float4*)(Us + (rq * 4 + r) * 128 + k4 * 4);
            float uk0 = uv.x, uk1 = uv.y, uk2 = uv.z, uk3 = uv.w;
            acc[r][0] = fmaf(uk0, wv[0].x, acc[r][0]);
            acc[r][1] = fmaf(uk0, wv[0].y, acc[r][1]);
            acc[r][2] = fmaf(uk0, wv[0].z, acc[r][2]);
            acc[r][3] = fmaf(uk0, wv[0].w, acc[r][3]);
            acc[r][0] = fmaf(uk1, wv[1].x, acc[r][0]);
            acc[r][1] = fmaf(uk1, wv[1].y, acc[r][1]);
            acc[r][2] = fmaf(uk1, wv[1].z, acc[r][2]);
            acc[r][3] = fmaf(uk1, wv[1].w, acc[r][3]);
            acc[r][0] = fmaf(uk2, wv[2].x, acc[r][0]);
            acc[r][1] = fmaf(uk2, wv[2].y, acc[r][1]);
            acc[r][2] = fmaf(uk2, wv[2].z, acc[r][2]);
            acc[r][3] = fmaf(uk2, wv[2].w, acc[r][3]);
            acc[r][0] = fmaf(uk3, wv[3].x, acc[r][0]);
            acc[r][1] = fmaf(uk3, wv[3].y, acc[r][1]);
            acc[r][2] = fmaf(uk3, wv[3].z, acc[r][2]);
            acc[r][3] = fmaf(uk3, wv[3].w, acc[r][3]);
        }
    }

    #pragma unroll
    for (int r = 0; r < 4; ++r) {
        float4 o;
        o.x = fmaxf(acc[r][0], 0.0f);
        o.y = fmaxf(acc[r][1], 0.0f);
        o.z = fmaxf(acc[r][2], 0.0f);
        o.w = fmaxf(acc[r][3], 0.0f);
        *(float4*)(Z + (size_t)(sbase + rq * 4 + r) * 256 + jq * 4) = o;
    }
}

// ------------------------------------------------------------------- sinkhorn
// One wave per OT; each wave uses only its own LDS slice -> NO __syncthreads.
// Packed-fp32 (v_pk_*) arithmetic throughout. Phase A: 2 log-domain iters.
// Phase B: absorbed exp-domain u=1/(K v), v=1/(K^T u), K in 16 f2 regs per
// layout; re-absorb on schedule {6,6,12,12,12}.
__global__ __launch_bounds__(256) void k_sinkhorn(
        const float* __restrict__ Z, float* __restrict__ dist) {
    __shared__ __align__(16) float sX[4][256];
    __shared__ __align__(16) float sY[4][256];
    __shared__ __align__(16) float sf[4][32];
    __shared__ __align__(16) float sg[4][32];
    __shared__ __align__(16) float su[4][32];
    __shared__ __align__(16) float sv[4][32];

    int w = threadIdx.x >> 6;
    int lane = threadIdx.x & 63;
    int task = blockIdx.x * 4 + w;            // grid is exact: 6144*4 = 24576
    int b = task / 3;
    int kind = task - 3 * b;                  // 0: (a,b)  1: (a,a)  2: (b,b)
    int sx = (kind == 2) ? (N_PAIRS + b) : b;
    int sy = (kind == 1) ? b : (N_PAIRS + b);

    *(float4*)(&sX[w][lane * 4]) = ((const float4*)(Z + (size_t)sx * 256))[lane];
    *(float4*)(&sY[w][lane * 4]) = ((const float4*)(Z + (size_t)sy * 256))[lane];
    sg[w][lane & 31] = 0.0f;

    const float CSCALE = -INV_EPS * LOG2E_F;
    const float CBIAS  = -LN32_F * LOG2E_F;

    int i_r = lane & 31, jh = lane >> 5;
    int j_c = lane & 31, ih = lane >> 5;

    f2 CrowV[8], CcolV[8];   // 16 entries each, packed
    {
        const f2* xp = (const f2*)(&sX[w][i_r * 8]);
        f2 x0 = xp[0], x1 = xp[1], x2 = xp[2], x3 = xp[3];
        #pragma unroll
        for (int t = 0; t < 16; ++t) {
            int j = jh * 16 + t;
            const f2* yp = (const f2*)(&sY[w][j * 8]);
            f2 d, s2;
            d = x0 - yp[0]; s2 = d * d;
            d = x1 - yp[1]; s2 = __builtin_elementwise_fma(d, d, s2);
            d = x2 - yp[2]; s2 = __builtin_elementwise_fma(d, d, s2);
            d = x3 - yp[3]; s2 = __builtin_elementwise_fma(d, d, s2);
            float d2 = s2.x + s2.y + 1e-12f;
            CrowV[t >> 1][t & 1] = fmaf(__builtin_amdgcn_sqrtf(d2), CSCALE, CBIAS);
        }
        const f2* yp = (const f2*)(&sY[w][j_c * 8]);
        f2 y0 = yp[0], y1 = yp[1], y2 = yp[2], y3 = yp[3];
        #pragma unroll
        for (int t = 0; t < 16; ++t) {
            int i = ih * 16 + t;
            const f2* qp = (const f2*)(&sX[w][i * 8]);
            f2 d, s2;
            d = qp[0] - y0; s2 = d * d;
            d = qp[1] - y1; s2 = __builtin_elementwise_fma(d, d, s2);
            d = qp[2] - y2; s2 = __builtin_elementwise_fma(d, d, s2);
            d = qp[3] - y3; s2 = __builtin_elementwise_fma(d, d, s2);
            float d2 = s2.x + s2.y + 1e-12f;
            CcolV[t >> 1][t & 1] = fmaf(__builtin_amdgcn_sqrtf(d2), CSCALE, CBIAS);
        }
    }

    float ft = 0.0f, gt = 0.0f;

    // ---- Phase A: 2 log-domain iterations
    #pragma unroll 1
    for (int it = 0; it < 2; ++it) {
        {
            const float4* gp = (const float4*)(&sg[w][jh * 16]);
            float4 G0 = gp[0], G1 = gp[1], G2 = gp[2], G3 = gp[3];
            f2 gv[8] = {f2{G0.x, G0.y}, f2{G0.z, G0.w}, f2{G1.x, G1.y}, f2{G1.z, G1.w},
                        f2{G2.x, G2.y}, f2{G2.z, G2.w}, f2{G3.x, G3.y}, f2{G3.z, G3.w}};
            f2 val[8], m2 = f2{-1e30f, -1e30f};
            #pragma unroll
            for (int t2 = 0; t2 < 8; ++t2) {
                val[t2] = gv[t2] + CrowV[t2];
                m2 = __builtin_elementwise_max(m2, val[t2]);
            }
            float m = fmaxf(m2.x, m2.y);
            m = fmaxf(m, __shfl_xor(m, 32));
            f2 mm = f2{m, m};
            float s0 = 0.0f, s1 = 0.0f;
            #pragma unroll
            for (int t2 = 0; t2 < 8; ++t2) {
                f2 e = val[t2] - mm;
                s0 += __builtin_amdgcn_exp2f(e.x);
                s1 += __builtin_amdgcn_exp2f(e.y);
            }
            float s = s0 + s1;
            s += __shfl_xor(s, 32);
            ft = -(m + __builtin_amdgcn_logf(s));   // v_log_f32 = log2
        }
        sf[w][lane & 31] = ft;
        {
            const float4* fp = (const float4*)(&sf[w][ih * 16]);
            float4 F0 = fp[0], F1 = fp[1], F2 = fp[2], F3 = fp[3];
            f2 fv[8] = {f2{F0.x, F0.y}, f2{F0.z, F0.w}, f2{F1.x, F1.y}, f2{F1.z, F1.w},
                        f2{F2.x, F2.y}, f2{F2.z, F2.w}, f2{F3.x, F3.y}, f2{F3.z, F3.w}};
            f2 val[8], m2 = f2{-1e30f, -1e30f};
            #pragma unroll
            for (int t2 = 0; t2 < 8; ++t2) {
                val[t2] = fv[t2] + CcolV[t2];
                m2 = __builtin_elementwise_max(m2, val[t2]);
            }
            float m = fmaxf(m2.x, m2.y);
            m = fmaxf(m, __shfl_xor(m, 32));
            f2 mm = f2{m, m};
            float s0 = 0.0f, s1 = 0.0f;
            #pragma unroll
            for (int t2 = 0; t2 < 8; ++t2) {
                f2 e = val[t2] - mm;
                s0 += __builtin_amdgcn_exp2f(e.x);
                s1 += __builtin_amdgcn_exp2f(e.y);
            }
            float s = s0 + s1;
            s += __shfl_xor(s, 32);
            gt = -(m + __builtin_amdgcn_logf(s));
        }
        sg[w][lane & 31] = gt;
    }

    // ---- Phase B: absorbed exp-domain
    f2 KR2[8], KC2[8];
    float ureg = 1.0f, vreg = 1.0f;

    auto absorb = [&]() {
        const float4* gp = (const float4*)(&sg[w][jh * 16]);
        float4 G0 = gp[0], G1 = gp[1], G2 = gp[2], G3 = gp[3];
        f2 gv[8] = {f2{G0.x, G0.y}, f2{G0.z, G0.w}, f2{G1.x, G1.y}, f2{G1.z, G1.w},
                    f2{G2.x, G2.y}, f2{G2.z, G2.w}, f2{G3.x, G3.y}, f2{G3.z, G3.w}};
        f2 ftv = f2{ft, ft};
        #pragma unroll
        for (int t2 = 0; t2 < 8; ++t2) {
            f2 a = (gv[t2] + CrowV[t2]) + ftv;
            KR2[t2].x = __builtin_amdgcn_exp2f(a.x);
            KR2[t2].y = __builtin_amdgcn_exp2f(a.y);
        }
        const float4* fp = (const float4*)(&sf[w][ih * 16]);
        float4 F0 = fp[0], F1 = fp[1], F2 = fp[2], F3 = fp[3];
        f2 fv[8] = {f2{F0.x, F0.y}, f2{F0.z, F0.w}, f2{F1.x, F1.y}, f2{F1.z, F1.w},
                    f2{F2.x, F2.y}, f2{F2.z, F2.w}, f2{F3.x, F3.y}, f2{F3.z, F3.w}};
        f2 gtv = f2{gt, gt};
        #pragma unroll
        for (int t2 = 0; t2 < 8; ++t2) {
            f2 a = (fv[t2] + CcolV[t2]) + gtv;
            KC2[t2].x = __builtin_amdgcn_exp2f(a.x);
            KC2[t2].y = __builtin_amdgcn_exp2f(a.y);
        }
        sv[w][lane & 31] = 1.0f;
        ureg = 1.0f;
        vreg = 1.0f;
    };

    const int blens[5] = {6, 6, 12, 12, 12};   // 48 exp iters total
    absorb();
    #pragma unroll 1
    for (int blk = 0; blk < 5; ++blk) {
        int L = blens[blk];
        #pragma unroll 2
        for (int s6 = 0; s6 < L; ++s6) {
            // f-step: u = 1/(KR . v)
            {
                const float4* vp = (const float4*)(&sv[w][jh * 16]);
                float4 A0 = vp[0], A1 = vp[1], A2 = vp[2], A3 = vp[3];
                f2 acc0 = KR2[0] * f2{A0.x, A0.y};
                f2 acc1 = KR2[1] * f2{A0.z, A0.w};
                acc0 = __builtin_elementwise_fma(KR2[2], f2{A1.x, A1.y}, acc0);
                acc1 = __builtin_elementwise_fma(KR2[3], f2{A1.z, A1.w}, acc1);
                acc0 = __builtin_elementwise_fma(KR2[4], f2{A2.x, A2.y}, acc0);
                acc1 = __builtin_elementwise_fma(KR2[5], f2{A2.z, A2.w}, acc1);
                acc0 = __builtin_elementwise_fma(KR2[6], f2{A3.x, A3.y}, acc0);
                acc1 = __builtin_elementwise_fma(KR2[7], f2{A3.z, A3.w}, acc1);
                f2 a = acc0 + acc1;
                float S = a.x + a.y;
                S += __shfl_xor(S, 32);
                ureg = __builtin_amdgcn_rcpf(S);
            }
            su[w][lane & 31] = ureg;
            // g-step: v = 1/(KC . u)
            {
                const float4* up = (const float4*)(&su[w][ih * 16]);
                float4 A0 = up[0], A1 = up[1], A2 = up[2], A3 = up[3];
                f2 acc0 = KC2[0] * f2{A0.x, A0.y};
                f2 acc1 = KC2[1] * f2{A0.z, A0.w};
                acc0 = __builtin_elementwise_fma(KC2[2], f2{A1.x, A1.y}, acc0);
                acc1 = __builtin_elementwise_fma(KC2[3], f2{A1.z, A1.w}, acc1);
                acc0 = __builtin_elementwise_fma(KC2[4], f2{A2.x, A2.y}, acc0);
                acc1 = __builtin_elementwise_fma(KC2[5], f2{A2.z, A2.w}, acc1);
                acc0 = __builtin_elementwise_fma(KC2[6], f2{A3.x, A3.y}, acc0);
                acc1 = __builtin_elementwise_fma(KC2[7], f2{A3.z, A3.w}, acc1);
                f2 a = acc0 + acc1;
                float T = a.x + a.y;
                T += __shfl_xor(T, 32);
                vreg = __builtin_amdgcn_rcpf(T);
            }
            sv[w][lane & 31] = vreg;
        }
        if (blk < 4) {
            ft += __builtin_amdgcn_logf(ureg);
            gt += __builtin_amdgcn_logf(vreg);
            sf[w][lane & 31] = ft;
            sg[w][lane & 31] = gt;
            absorb();
        }
    }
    ft += __builtin_amdgcn_logf(ureg);
    gt += __builtin_amdgcn_logf(vreg);

    // dual cost = eps*ln2*(sum f~ + sum g~)/32; wave sum double-counts -> /64.
    float v = ft + gt;
    #pragma unroll
    for (int off = 32; off > 0; off >>= 1) v += __shfl_xor(v, off);
    if (lane == 0) {
        float cost = v * (EPS_F * LN2_F / 64.0f);
        float wgt = (kind == 0) ? 1.0f : -0.5f;
        unsafeAtomicAdd(&dist[b], wgt * cost);
    }
}

// ------------------------------------------------------------------ finalize
__global__ void k_finalize(const float* __restrict__ dist,
                           const float* __restrict__ gd, float* __restrict__ out) {
    __shared__ float red[256];
    float s = 0.0f;
    for (int i = threadIdx.x; i < N_PAIRS; i += 256) {
        float g = gd[i];
        s += fabsf(dist[i] - g) / g;
    }
    red[threadIdx.x] = s;
    __syncthreads();
    for (int o = 128; o > 0; o >>= 1) {
        if (threadIdx.x < o) red[threadIdx.x] += red[threadIdx.x + o];
        __syncthreads();
    }
    if (threadIdx.x == 0) out[0] = red[0] * (1.0f / N_PAIRS);
}

// -------------------------------------------------------------------- launch
extern "C" void kernel_launch(void* const* d_in, const int* in_sizes, int n_in,
                              void* d_out, int out_size, void* d_ws, size_t ws_size,
                              hipStream_t stream) {
    const float* x    = (const float*)d_in[0];   // [50000,128]
    const float* W    = (const float*)d_in[1];   // [128,256]
    const int*   eidx = (const int*)d_in[2];     // [2,800000]
    const int*   pair = (const int*)d_in[3];     // [2,8192] flat = 16384 slots
    const float* gd   = (const float*)d_in[4];   // [8192]

    char* ws = (char*)d_ws;
    size_t off = 0;
    int*   cnt    = (int*)  (ws + off); off += (size_t)N_NODES * 4;
    int*   flags  = (int*)  (ws + off); off += (size_t)N_NODES * 4;
    float* dist   = (float*)(ws + off); off += (size_t)N_PAIRS * 4;
    size_t zero_bytes = off;                     // cnt+flags+dist contiguous
    int*   bucket = (int*)  (ws + off); off += (size_t)N_NODES * CAP * 4; // 12.8 MB
    float* Z      = (float*)(ws + off); off += (size_t)N_SLOTS * 256 * 4; // 16.8 MB

    hipMemsetAsync(d_ws, 0, zero_bytes, stream);
    k_mark    <<<(N_SLOTS + 255) / 256, 256, 0, stream>>>(pair, flags);
    k_scatter <<<N_EDGES / 256, 256, 0, stream>>>(eidx, flags, cnt, bucket);
    k_gemm    <<<N_SLOTS / 16, 256, 0, stream>>>(pair, x, cnt, bucket, W, Z);
    k_sinkhorn<<<(3 * N_PAIRS) / 4, 256, 0, stream>>>(Z, dist);
    k_finalize<<<1, 256, 0, stream>>>(dist, gd, (float*)d_out);
}

// Round 6
// 261.635 us; speedup vs baseline: 3.4046x; 1.1188x over previous
//
#include <hip/hip_runtime.h>

#define N_NODES 50000
#define N_EDGES 800000
#define N_PAIRS 8192
#define N_SLOTS (2 * N_PAIRS)
#define CAP     64          // per-node bucket capacity; P(deg>63)~5e-19

// Sinkhorn constants (log2 domain):
//   Crow2 = -(C/eps + ln32)*log2e ; potentials kept in /(eps*ln2) units
#define INV_EPS   20.0f
#define LOG2E_F   1.4426950408889634f
#define LN2_F     0.6931471805599453f
#define LN32_F    3.4657359027997265f
#define EPS_F     0.05f

typedef float f2 __attribute__((ext_vector_type(2)));

// ---------------------------------------------------------------- mark needed
__global__ void k_mark(const int* __restrict__ pairs, int* __restrict__ flags) {
    int t = blockIdx.x * 256 + threadIdx.x;
    if (t < N_SLOTS) flags[pairs[t]] = 1;
}

// ---------------------------------------- scatter into fixed-cap buckets
__global__ __launch_bounds__(256) void k_scatter(
        const int* __restrict__ eidx, const int* __restrict__ flags,
        int* __restrict__ cnt, int* __restrict__ bucket) {
    int t = blockIdx.x * 256 + threadIdx.x;   // exact grid: 800000/256
    int dst = eidx[N_EDGES + t];
    if (!flags[dst]) return;
    int pos = atomicAdd(&cnt[dst], 1);
    if (pos < CAP) bucket[dst * CAP + pos] = eidx[t];
}

// ------------------------------------ fused gather + GEMM + relu
__global__ __launch_bounds__(256) void k_gemm(
        const int* __restrict__ pairs, const float* __restrict__ x,
        const int* __restrict__ cnt, const int* __restrict__ bucket,
        const float* __restrict__ W, float* __restrict__ Z) {
    __shared__ __align__(16) float Us[16 * 128];
    int sbase = blockIdx.x * 16;
    int t = threadIdx.x;
    int wave = t >> 6, lane = t & 63;

    #pragma unroll
    for (int rr = 0; rr < 4; ++rr) {
        int r = wave * 4 + rr;
        int node = pairs[sbase + r];
        int n = cnt[node];
        int m = (n < CAP) ? n : CAP;
        const int* bk = bucket + node * CAP;
        float ax = 0.0f, ay = 0.0f;
        int k = 0;
        for (; k + 4 <= m; k += 4) {
            int s0 = bk[k], s1 = bk[k + 1], s2 = bk[k + 2], s3 = bk[k + 3];
            float2 v0 = *(const float2*)(x + (size_t)s0 * 128 + lane * 2);
            float2 v1 = *(const float2*)(x + (size_t)s1 * 128 + lane * 2);
            float2 v2 = *(const float2*)(x + (size_t)s2 * 128 + lane * 2);
            float2 v3 = *(const float2*)(x + (size_t)s3 * 128 + lane * 2);
            ax += (v0.x + v1.x) + (v2.x + v3.x);
            ay += (v0.y + v1.y) + (v2.y + v3.y);
        }
        for (; k < m; ++k) {
            int s0 = bk[k];
            float2 v0 = *(const float2*)(x + (size_t)s0 * 128 + lane * 2);
            ax += v0.x;
            ay += v0.y;
        }
        float rdeg = 1.0f / fmaxf((float)n, 1.0f);
        float2 xv = *(const float2*)(x + (size_t)node * 128 + lane * 2);
        float2 o;
        o.x = fmaf(ax, rdeg, xv.x);
        o.y = fmaf(ay, rdeg, xv.y);
        *(float2*)(Us + r * 128 + lane * 2) = o;
    }
    __syncthreads();

    int jq = t & 63;   // column quad: cols 4*jq..4*jq+3
    int rq = t >> 6;   // row quad group: rows 4*rq..4*rq+3
    float acc[4][4] = {};
    const float4* Wv = (const float4*)W;   // W[128][256]

    for (int k4 = 0; k4 < 32; ++k4) {
        float4 wv[4];
        #pragma unroll
        for (int i = 0; i < 4; ++i) wv[i] = Wv[(size_t)(k4 * 4 + i) * 64 + jq];
        #pragma unroll
        for (int r = 0; r < 4; ++r) {
            float4 uv = *(const float4*)(Us + (rq * 4 + r) * 128 + k4 * 4);
            float uk0 = uv.x, uk1 = uv.y, uk2 = uv.z, uk3 = uv.w;
            acc[r][0] = fmaf(uk0, wv[0].x, acc[r][0]);
            acc[r][1] = fmaf(uk0, wv[0].y, acc[r][1]);
            acc[r][2] = fmaf(uk0, wv[0].z, acc[r][2]);
            acc[r][3] = fmaf(uk0, wv[0].w, acc[r][3]);
            acc[r][0] = fmaf(uk1, wv[1].x, acc[r][0]);
            acc[r][1] = fmaf(uk1, wv[1].y, acc[r][1]);
            acc[r][2] = fmaf(uk1, wv[1].z, acc[r][2]);
            acc[r][3] = fmaf(uk1, wv[1].w, acc[r][3]);
            acc[r][0] = fmaf(uk2, wv[2].x, acc[r][0]);
            acc[r][1] = fmaf(uk2, wv[2].y, acc[r][1]);
            acc[r][2] = fmaf(uk2, wv[2].z, acc[r][2]);
            acc[r][3] = fmaf(uk2, wv[2].w, acc[r][3]);
            acc[r][0] = fmaf(uk3, wv[3].x, acc[r][0]);
            acc[r][1] = fmaf(uk3, wv[3].y, acc[r][1]);
            acc[r][2] = fmaf(uk3, wv[3].z, acc[r][2]);
            acc[r][3] = fmaf(uk3, wv[3].w, acc[r][3]);
        }
    }

    #pragma unroll
    for (int r = 0; r < 4; ++r) {
        float4 o;
        o.x = fmaxf(acc[r][0], 0.0f);
        o.y = fmaxf(acc[r][1], 0.0f);
        o.z = fmaxf(acc[r][2], 0.0f);
        o.w = fmaxf(acc[r][3], 0.0f);
        *(float4*)(Z + (size_t)(sbase + rq * 4 + r) * 256 + jq * 4) = o;
    }
}

// ------------------------------------------------------------------- sinkhorn
// One dispatch, two block-uniform paths, 10KB LDS overlay per block:
//  blocks [0,2048):   off-diagonal OT(a,b), one wave per pair (R5 scheme:
//                     alternating absorbed exp-domain, butterfly over halves)
//  blocks [2048,4096): diagonal OTs — one wave handles (a,a) in half 0 and
//                     (b,b) in half 1. Symmetric C collapses the alternation
//                     to z_{n+1}=T(z_n); z_99=f_50, z_100=g_50. Full 32-dot
//                     per lane -> NO cross-lane shuffles in the loop.
__global__ __launch_bounds__(256) void k_sinkhorn(
        const float* __restrict__ Z, float* __restrict__ dist) {
    __shared__ __align__(16) float smem[4][640];   // 10240 B

    int w = threadIdx.x >> 6;
    int lane = threadIdx.x & 63;
    const float CSCALE = -INV_EPS * LOG2E_F;
    const float CBIAS  = -LN32_F * LOG2E_F;

    if (blockIdx.x < 2048) {
        // ================= off-diagonal path: OT(a,b) =================
        float* sX = &smem[w][0];
        float* sY = &smem[w][256];
        float* sf = &smem[w][512];
        float* sg = &smem[w][544];
        float* su = &smem[w][576];
        float* sv = &smem[w][608];

        int b = blockIdx.x * 4 + w;               // 2048*4 = 8192 pairs
        int sx = b, sy = N_PAIRS + b;

        *(float4*)(&sX[lane * 4]) = ((const float4*)(Z + (size_t)sx * 256))[lane];
        *(float4*)(&sY[lane * 4]) = ((const float4*)(Z + (size_t)sy * 256))[lane];
        sg[lane & 31] = 0.0f;

        int i_r = lane & 31, jh = lane >> 5;
        int j_c = lane & 31, ih = lane >> 5;

        f2 CrowV[8], CcolV[8];
        {
            const f2* xp = (const f2*)(&sX[i_r * 8]);
            f2 x0 = xp[0], x1 = xp[1], x2 = xp[2], x3 = xp[3];
            #pragma unroll
            for (int t = 0; t < 16; ++t) {
                int j = jh * 16 + t;
                const f2* yp = (const f2*)(&sY[j * 8]);
                f2 d, s2;
                d = x0 - yp[0]; s2 = d * d;
                d = x1 - yp[1]; s2 = __builtin_elementwise_fma(d, d, s2);
                d = x2 - yp[2]; s2 = __builtin_elementwise_fma(d, d, s2);
                d = x3 - yp[3]; s2 = __builtin_elementwise_fma(d, d, s2);
                float d2 = s2.x + s2.y + 1e-12f;
                CrowV[t >> 1][t & 1] = fmaf(__builtin_amdgcn_sqrtf(d2), CSCALE, CBIAS);
            }
            const f2* yp = (const f2*)(&sY[j_c * 8]);
            f2 y0 = yp[0], y1 = yp[1], y2 = yp[2], y3 = yp[3];
            #pragma unroll
            for (int t = 0; t < 16; ++t) {
                int i = ih * 16 + t;
                const f2* qp = (const f2*)(&sX[i * 8]);
                f2 d, s2;
                d = qp[0] - y0; s2 = d * d;
                d = qp[1] - y1; s2 = __builtin_elementwise_fma(d, d, s2);
                d = qp[2] - y2; s2 = __builtin_elementwise_fma(d, d, s2);
                d = qp[3] - y3; s2 = __builtin_elementwise_fma(d, d, s2);
                float d2 = s2.x + s2.y + 1e-12f;
                CcolV[t >> 1][t & 1] = fmaf(__builtin_amdgcn_sqrtf(d2), CSCALE, CBIAS);
            }
        }

        float ft = 0.0f, gt = 0.0f;

        // Phase A: 2 log-domain iterations
        #pragma unroll 1
        for (int it = 0; it < 2; ++it) {
            {
                const float4* gp = (const float4*)(&sg[jh * 16]);
                float4 G0 = gp[0], G1 = gp[1], G2 = gp[2], G3 = gp[3];
                f2 gv[8] = {f2{G0.x, G0.y}, f2{G0.z, G0.w}, f2{G1.x, G1.y}, f2{G1.z, G1.w},
                            f2{G2.x, G2.y}, f2{G2.z, G2.w}, f2{G3.x, G3.y}, f2{G3.z, G3.w}};
                f2 val[8], m2 = f2{-1e30f, -1e30f};
                #pragma unroll
                for (int t2 = 0; t2 < 8; ++t2) {
                    val[t2] = gv[t2] + CrowV[t2];
                    m2 = __builtin_elementwise_max(m2, val[t2]);
                }
                float m = fmaxf(m2.x, m2.y);
                m = fmaxf(m, __shfl_xor(m, 32));
                f2 mm = f2{m, m};
                float s0 = 0.0f, s1 = 0.0f;
                #pragma unroll
                for (int t2 = 0; t2 < 8; ++t2) {
                    f2 e = val[t2] - mm;
                    s0 += __builtin_amdgcn_exp2f(e.x);
                    s1 += __builtin_amdgcn_exp2f(e.y);
                }
                float s = s0 + s1;
                s += __shfl_xor(s, 32);
                ft = -(m + __builtin_amdgcn_logf(s));
            }
            sf[lane & 31] = ft;
            {
                const float4* fp = (const float4*)(&sf[ih * 16]);
                float4 F0 = fp[0], F1 = fp[1], F2 = fp[2], F3 = fp[3];
                f2 fv[8] = {f2{F0.x, F0.y}, f2{F0.z, F0.w}, f2{F1.x, F1.y}, f2{F1.z, F1.w},
                            f2{F2.x, F2.y}, f2{F2.z, F2.w}, f2{F3.x, F3.y}, f2{F3.z, F3.w}};
                f2 val[8], m2 = f2{-1e30f, -1e30f};
                #pragma unroll
                for (int t2 = 0; t2 < 8; ++t2) {
                    val[t2] = fv[t2] + CcolV[t2];
                    m2 = __builtin_elementwise_max(m2, val[t2]);
                }
                float m = fmaxf(m2.x, m2.y);
                m = fmaxf(m, __shfl_xor(m, 32));
                f2 mm = f2{m, m};
                float s0 = 0.0f, s1 = 0.0f;
                #pragma unroll
                for (int t2 = 0; t2 < 8; ++t2) {
                    f2 e = val[t2] - mm;
                    s0 += __builtin_amdgcn_exp2f(e.x);
                    s1 += __builtin_amdgcn_exp2f(e.y);
                }
                float s = s0 + s1;
                s += __shfl_xor(s, 32);
                gt = -(m + __builtin_amdgcn_logf(s));
            }
            sg[lane & 31] = gt;
        }

        // Phase B: absorbed exp-domain
        f2 KR2[8], KC2[8];
        float ureg = 1.0f, vreg = 1.0f;

        auto absorb = [&]() {
            const float4* gp = (const float4*)(&sg[jh * 16]);
            float4 G0 = gp[0], G1 = gp[1], G2 = gp[2], G3 = gp[3];
            f2 gv[8] = {f2{G0.x, G0.y}, f2{G0.z, G0.w}, f2{G1.x, G1.y}, f2{G1.z, G1.w},
                        f2{G2.x, G2.y}, f2{G2.z, G2.w}, f2{G3.x, G3.y}, f2{G3.z, G3.w}};
            f2 ftv = f2{ft, ft};
            #pragma unroll
            for (int t2 = 0; t2 < 8; ++t2) {
                f2 a = (gv[t2] + CrowV[t2]) + ftv;
                KR2[t2].x = __builtin_amdgcn_exp2f(a.x);
                KR2[t2].y = __builtin_amdgcn_exp2f(a.y);
            }
            const float4* fp = (const float4*)(&sf[ih * 16]);
            float4 F0 = fp[0], F1 = fp[1], F2 = fp[2], F3 = fp[3];
            f2 fv[8] = {f2{F0.x, F0.y}, f2{F0.z, F0.w}, f2{F1.x, F1.y}, f2{F1.z, F1.w},
                        f2{F2.x, F2.y}, f2{F2.z, F2.w}, f2{F3.x, F3.y}, f2{F3.z, F3.w}};
            f2 gtv = f2{gt, gt};
            #pragma unroll
            for (int t2 = 0; t2 < 8; ++t2) {
                f2 a = (fv[t2] + CcolV[t2]) + gtv;
                KC2[t2].x = __builtin_amdgcn_exp2f(a.x);
                KC2[t2].y = __builtin_amdgcn_exp2f(a.y);
            }
            sv[lane & 31] = 1.0f;
            ureg = 1.0f;
            vreg = 1.0f;
        };

        const int blens[5] = {6, 6, 12, 12, 12};   // 48 exp iters total
        absorb();
        #pragma unroll 1
        for (int blk = 0; blk < 5; ++blk) {
            int L = blens[blk];
            #pragma unroll 2
            for (int s6 = 0; s6 < L; ++s6) {
                {
                    const float4* vp = (const float4*)(&sv[jh * 16]);
                    float4 A0 = vp[0], A1 = vp[1], A2 = vp[2], A3 = vp[3];
                    f2 acc0 = KR2[0] * f2{A0.x, A0.y};
                    f2 acc1 = KR2[1] * f2{A0.z, A0.w};
                    acc0 = __builtin_elementwise_fma(KR2[2], f2{A1.x, A1.y}, acc0);
                    acc1 = __builtin_elementwise_fma(KR2[3], f2{A1.z, A1.w}, acc1);
                    acc0 = __builtin_elementwise_fma(KR2[4], f2{A2.x, A2.y}, acc0);
                    acc1 = __builtin_elementwise_fma(KR2[5], f2{A2.z, A2.w}, acc1);
                    acc0 = __builtin_elementwise_fma(KR2[6], f2{A3.x, A3.y}, acc0);
                    acc1 = __builtin_elementwise_fma(KR2[7], f2{A3.z, A3.w}, acc1);
                    f2 a = acc0 + acc1;
                    float S = a.x + a.y;
                    S += __shfl_xor(S, 32);
                    ureg = __builtin_amdgcn_rcpf(S);
                }
                su[lane & 31] = ureg;
                {
                    const float4* up = (const float4*)(&su[ih * 16]);
                    float4 A0 = up[0], A1 = up[1], A2 = up[2], A3 = up[3];
                    f2 acc0 = KC2[0] * f2{A0.x, A0.y};
                    f2 acc1 = KC2[1] * f2{A0.z, A0.w};
                    acc0 = __builtin_elementwise_fma(KC2[2], f2{A1.x, A1.y}, acc0);
                    acc1 = __builtin_elementwise_fma(KC2[3], f2{A1.z, A1.w}, acc1);
                    acc0 = __builtin_elementwise_fma(KC2[4], f2{A2.x, A2.y}, acc0);
                    acc1 = __builtin_elementwise_fma(KC2[5], f2{A2.z, A2.w}, acc1);
                    acc0 = __builtin_elementwise_fma(KC2[6], f2{A3.x, A3.y}, acc0);
                    acc1 = __builtin_elementwise_fma(KC2[7], f2{A3.z, A3.w}, acc1);
                    f2 a = acc0 + acc1;
                    float T = a.x + a.y;
                    T += __shfl_xor(T, 32);
                    vreg = __builtin_amdgcn_rcpf(T);
                }
                sv[lane & 31] = vreg;
            }
            if (blk < 4) {
                ft += __builtin_amdgcn_logf(ureg);
                gt += __builtin_amdgcn_logf(vreg);
                sf[lane & 31] = ft;
                sg[lane & 31] = gt;
                absorb();
            }
        }
        ft += __builtin_amdgcn_logf(ureg);
        gt += __builtin_amdgcn_logf(vreg);

        float v = ft + gt;
        #pragma unroll
        for (int off = 32; off > 0; off >>= 1) v += __shfl_xor(v, off);
        if (lane == 0) {
            float cost = v * (EPS_F * LN2_F / 64.0f);
            unsafeAtomicAdd(&dist[b], cost);
        }
    } else {
        // ================= diagonal path: OT(a,a) & OT(b,b) =================
        int h = lane >> 5, i = lane & 31;
        int P = (blockIdx.x - 2048) * 4 + w;      // 2048*4 = 8192 pairs
        int src = h ? (N_PAIRS + P) : P;

        float* sP  = &smem[w][h * 256];           // own half's cloud
        float* swv = &smem[w][512];               // w vector [h*32 + j]
        float* spv = &smem[w][576];               // p vector at absorb

        {
            const float4* zp = (const float4*)(Z + (size_t)src * 256);
            *(float4*)(&sP[i * 8])     = zp[i * 2];
            *(float4*)(&sP[i * 8 + 4]) = zp[i * 2 + 1];
        }

        f2 CV[16];
        {
            const f2* xp = (const f2*)(&sP[i * 8]);
            f2 x0 = xp[0], x1 = xp[1], x2 = xp[2], x3 = xp[3];
            #pragma unroll
            for (int j = 0; j < 32; ++j) {
                const f2* yp = (const f2*)(&sP[j * 8]);
                f2 d, s2;
                d = x0 - yp[0]; s2 = d * d;
                d = x1 - yp[1]; s2 = __builtin_elementwise_fma(d, d, s2);
                d = x2 - yp[2]; s2 = __builtin_elementwise_fma(d, d, s2);
                d = x3 - yp[3]; s2 = __builtin_elementwise_fma(d, d, s2);
                float d2 = s2.x + s2.y + 1e-12f;
                CV[j >> 1][j & 1] = fmaf(__builtin_amdgcn_sqrtf(d2), CSCALE, CBIAS);
            }
        }

        float pp = 0.0f, E = 1.0f, wcur = 1.0f, wprev = 1.0f;
        f2 KV[16];
        #pragma unroll
        for (int t = 0; t < 16; ++t) {
            KV[t].x = __builtin_amdgcn_exp2f(CV[t].x);
            KV[t].y = __builtin_amdgcn_exp2f(CV[t].y);
        }
        swv[lane] = 1.0f;

        const int blens[9] = {4, 12, 12, 12, 12, 12, 12, 12, 12};  // 100 T-steps
        #pragma unroll 1
        for (int blk = 0; blk < 9; ++blk) {
            int L = blens[blk];
            #pragma unroll 2
            for (int s = 0; s < L; ++s) {
                const float4* wp = (const float4*)(&swv[h * 32]);
                float4 A0 = wp[0], A1 = wp[1], A2 = wp[2], A3 = wp[3];
                float4 A4 = wp[4], A5 = wp[5], A6 = wp[6], A7 = wp[7];
                f2 acc0 = KV[0] * f2{A0.x, A0.y};
                f2 acc1 = KV[1] * f2{A0.z, A0.w};
                acc0 = __builtin_elementwise_fma(KV[2],  f2{A1.x, A1.y}, acc0);
                acc1 = __builtin_elementwise_fma(KV[3],  f2{A1.z, A1.w}, acc1);
                acc0 = __builtin_elementwise_fma(KV[4],  f2{A2.x, A2.y}, acc0);
                acc1 = __builtin_elementwise_fma(KV[5],  f2{A2.z, A2.w}, acc1);
                acc0 = __builtin_elementwise_fma(KV[6],  f2{A3.x, A3.y}, acc0);
                acc1 = __builtin_elementwise_fma(KV[7],  f2{A3.z, A3.w}, acc1);
                acc0 = __builtin_elementwise_fma(KV[8],  f2{A4.x, A4.y}, acc0);
                acc1 = __builtin_elementwise_fma(KV[9],  f2{A4.z, A4.w}, acc1);
                acc0 = __builtin_elementwise_fma(KV[10], f2{A5.x, A5.y}, acc0);
                acc1 = __builtin_elementwise_fma(KV[11], f2{A5.z, A5.w}, acc1);
                acc0 = __builtin_elementwise_fma(KV[12], f2{A6.x, A6.y}, acc0);
                acc1 = __builtin_elementwise_fma(KV[13], f2{A6.z, A6.w}, acc1);
                acc0 = __builtin_elementwise_fma(KV[14], f2{A7.x, A7.y}, acc0);
                acc1 = __builtin_elementwise_fma(KV[15], f2{A7.z, A7.w}, acc1);
                f2 a = acc0 + acc1;
                float S = a.x + a.y;
                wprev = wcur;
                wcur = __builtin_amdgcn_rcpf(S) * E;
                swv[h * 32 + i] = wcur;
            }
            if (blk < 8) {
                pp += __builtin_amdgcn_logf(wcur);
                spv[lane] = pp;
                const float4* pv = (const float4*)(&spv[h * 32]);
                float4 P0 = pv[0], P1 = pv[1], P2 = pv[2], P3 = pv[3];
                float4 P4 = pv[4], P5 = pv[5], P6 = pv[6], P7 = pv[7];
                f2 pj[16] = {f2{P0.x,P0.y}, f2{P0.z,P0.w}, f2{P1.x,P1.y}, f2{P1.z,P1.w},
                             f2{P2.x,P2.y}, f2{P2.z,P2.w}, f2{P3.x,P3.y}, f2{P3.z,P3.w},
                             f2{P4.x,P4.y}, f2{P4.z,P4.w}, f2{P5.x,P5.y}, f2{P5.z,P5.w},
                             f2{P6.x,P6.y}, f2{P6.z,P6.w}, f2{P7.x,P7.y}, f2{P7.z,P7.w}};
                #pragma unroll
                for (int t = 0; t < 16; ++t) {
                    f2 a = pj[t] + CV[t];
                    KV[t].x = __builtin_amdgcn_exp2f(a.x);
                    KV[t].y = __builtin_amdgcn_exp2f(a.y);
                }
                E = __builtin_amdgcn_exp2f(-pp);
                wcur = 1.0f;
                swv[lane] = 1.0f;
            }
        }

        // z99 = pp + log2(wprev), z100 = pp + log2(wcur); cost = eps*ln2*sum/32
        float zsum = 2.0f * pp + __builtin_amdgcn_logf(wprev)
                   + __builtin_amdgcn_logf(wcur);
        #pragma unroll
        for (int off = 16; off > 0; off >>= 1) zsum += __shfl_xor(zsum, off);
        if (i == 0) {
            float cost = zsum * (EPS_F * LN2_F / 32.0f);
            unsafeAtomicAdd(&dist[P], -0.5f * cost);
        }
    }
}

// ------------------------------------------------------------------ finalize
__global__ void k_finalize(const float* __restrict__ dist,
                           const float* __restrict__ gd, float* __restrict__ out) {
    __shared__ float red[256];
    float s = 0.0f;
    for (int i = threadIdx.x; i < N_PAIRS; i += 256) {
        float g = gd[i];
        s += fabsf(dist[i] - g) / g;
    }
    red[threadIdx.x] = s;
    __syncthreads();
    for (int o = 128; o > 0; o >>= 1) {
        if (threadIdx.x < o) red[threadIdx.x] += red[threadIdx.x + o];
        __syncthreads();
    }
    if (threadIdx.x == 0) out[0] = red[0] * (1.0f / N_PAIRS);
}

// -------------------------------------------------------------------- launch
extern "C" void kernel_launch(void* const* d_in, const int* in_sizes, int n_in,
                              void* d_out, int out_size, void* d_ws, size_t ws_size,
                              hipStream_t stream) {
    const float* x    = (const float*)d_in[0];   // [50000,128]
    const float* W    = (const float*)d_in[1];   // [128,256]
    const int*   eidx = (const int*)d_in[2];     // [2,800000]
    const int*   pair = (const int*)d_in[3];     // [2,8192] flat = 16384 slots
    const float* gd   = (const float*)d_in[4];   // [8192]

    char* ws = (char*)d_ws;
    size_t off = 0;
    int*   cnt    = (int*)  (ws + off); off += (size_t)N_NODES * 4;
    int*   flags  = (int*)  (ws + off); off += (size_t)N_NODES * 4;
    float* dist   = (float*)(ws + off); off += (size_t)N_PAIRS * 4;
    size_t zero_bytes = off;                     // cnt+flags+dist contiguous
    int*   bucket = (int*)  (ws + off); off += (size_t)N_NODES * CAP * 4; // 12.8 MB
    float* Z      = (float*)(ws + off); off += (size_t)N_SLOTS * 256 * 4; // 16.8 MB

    hipMemsetAsync(d_ws, 0, zero_bytes, stream);
    k_mark    <<<(N_SLOTS + 255) / 256, 256, 0, stream>>>(pair, flags);
    k_scatter <<<N_EDGES / 256, 256, 0, stream>>>(eidx, flags, cnt, bucket);
    k_gemm    <<<N_SLOTS / 16, 256, 0, stream>>>(pair, x, cnt, bucket, W, Z);
    k_sinkhorn<<<4096, 256, 0, stream>>>(Z, dist);
    k_finalize<<<1, 256, 0, stream>>>(dist, gd, (float*)d_out);
}

// Round 7
// 259.918 us; speedup vs baseline: 3.4271x; 1.0066x over previous
//
#include <hip/hip_runtime.h>

#define N_NODES 50000
#define N_EDGES 800000
#define N_PAIRS 8192
#define N_SLOTS (2 * N_PAIRS)
#define CAP     64          // per-node bucket capacity; P(deg>63)~5e-19

// Sinkhorn constants (log2 domain):
//   C2 = -(C/eps + ln32)*log2e ; potentials kept in /(eps*ln2) units
#define INV_EPS   20.0f
#define LOG2E_F   1.4426950408889634f
#define LN2_F     0.6931471805599453f
#define LN32_F    3.4657359027997265f
#define EPS_F     0.05f

typedef float f2 __attribute__((ext_vector_type(2)));

// ---------------------------------------------------------------- mark needed
__global__ void k_mark(const int* __restrict__ pairs, int* __restrict__ flags) {
    int t = blockIdx.x * 256 + threadIdx.x;
    if (t < N_SLOTS) flags[pairs[t]] = 1;
}

// ---------------------------------------- scatter into fixed-cap buckets
__global__ __launch_bounds__(256) void k_scatter(
        const int* __restrict__ eidx, const int* __restrict__ flags,
        int* __restrict__ cnt, int* __restrict__ bucket) {
    int t = blockIdx.x * 256 + threadIdx.x;   // exact grid: 800000/256
    int dst = eidx[N_EDGES + t];
    if (!flags[dst]) return;
    int pos = atomicAdd(&cnt[dst], 1);
    if (pos < CAP) bucket[dst * CAP + pos] = eidx[t];
}

// ------------------------------------ fused gather + GEMM + relu
__global__ __launch_bounds__(256) void k_gemm(
        const int* __restrict__ pairs, const float* __restrict__ x,
        const int* __restrict__ cnt, const int* __restrict__ bucket,
        const float* __restrict__ W, float* __restrict__ Z) {
    __shared__ __align__(16) float Us[16 * 128];
    int sbase = blockIdx.x * 16;
    int t = threadIdx.x;
    int wave = t >> 6, lane = t & 63;

    #pragma unroll
    for (int rr = 0; rr < 4; ++rr) {
        int r = wave * 4 + rr;
        int node = pairs[sbase + r];
        int n = cnt[node];
        int m = (n < CAP) ? n : CAP;
        const int* bk = bucket + node * CAP;
        float ax = 0.0f, ay = 0.0f;
        int k = 0;
        for (; k + 4 <= m; k += 4) {
            int s0 = bk[k], s1 = bk[k + 1], s2 = bk[k + 2], s3 = bk[k + 3];
            float2 v0 = *(const float2*)(x + (size_t)s0 * 128 + lane * 2);
            float2 v1 = *(const float2*)(x + (size_t)s1 * 128 + lane * 2);
            float2 v2 = *(const float2*)(x + (size_t)s2 * 128 + lane * 2);
            float2 v3 = *(const float2*)(x + (size_t)s3 * 128 + lane * 2);
            ax += (v0.x + v1.x) + (v2.x + v3.x);
            ay += (v0.y + v1.y) + (v2.y + v3.y);
        }
        for (; k < m; ++k) {
            int s0 = bk[k];
            float2 v0 = *(const float2*)(x + (size_t)s0 * 128 + lane * 2);
            ax += v0.x;
            ay += v0.y;
        }
        float rdeg = 1.0f / fmaxf((float)n, 1.0f);
        float2 xv = *(const float2*)(x + (size_t)node * 128 + lane * 2);
        float2 o;
        o.x = fmaf(ax, rdeg, xv.x);
        o.y = fmaf(ay, rdeg, xv.y);
        *(float2*)(Us + r * 128 + lane * 2) = o;
    }
    __syncthreads();

    int jq = t & 63;   // column quad: cols 4*jq..4*jq+3
    int rq = t >> 6;   // row quad group: rows 4*rq..4*rq+3
    float acc[4][4] = {};
    const float4* Wv = (const float4*)W;   // W[128][256]

    for (int k4 = 0; k4 < 32; ++k4) {
        float4 wv[4];
        #pragma unroll
        for (int i = 0; i < 4; ++i) wv[i] = Wv[(size_t)(k4 * 4 + i) * 64 + jq];
        #pragma unroll
        for (int r = 0; r < 4; ++r) {
            float4 uv = *(const float4*)(Us + (rq * 4 + r) * 128 + k4 * 4);
            float uk0 = uv.x, uk1 = uv.y, uk2 = uv.z, uk3 = uv.w;
            acc[r][0] = fmaf(uk0, wv[0].x, acc[r][0]);
            acc[r][1] = fmaf(uk0, wv[0].y, acc[r][1]);
            acc[r][2] = fmaf(uk0, wv[0].z, acc[r][2]);
            acc[r][3] = fmaf(uk0, wv[0].w, acc[r][3]);
            acc[r][0] = fmaf(uk1, wv[1].x, acc[r][0]);
            acc[r][1] = fmaf(uk1, wv[1].y, acc[r][1]);
            acc[r][2] = fmaf(uk1, wv[1].z, acc[r][2]);
            acc[r][3] = fmaf(uk1, wv[1].w, acc[r][3]);
            acc[r][0] = fmaf(uk2, wv[2].x, acc[r][0]);
            acc[r][1] = fmaf(uk2, wv[2].y, acc[r][1]);
            acc[r][2] = fmaf(uk2, wv[2].z, acc[r][2]);
            acc[r][3] = fmaf(uk2, wv[2].w, acc[r][3]);
            acc[r][0] = fmaf(uk3, wv[3].x, acc[r][0]);
            acc[r][1] = fmaf(uk3, wv[3].y, acc[r][1]);
            acc[r][2] = fmaf(uk3, wv[3].z, acc[r][2]);
            acc[r][3] = fmaf(uk3, wv[3].w, acc[r][3]);
        }
    }

    #pragma unroll
    for (int r = 0; r < 4; ++r) {
        float4 o;
        o.x = fmaxf(acc[r][0], 0.0f);
        o.y = fmaxf(acc[r][1], 0.0f);
        o.z = fmaxf(acc[r][2], 0.0f);
        o.w = fmaxf(acc[r][3], 0.0f);
        *(float4*)(Z + (size_t)(sbase + rq * 4 + r) * 256 + jq * 4) = o;
    }
}

// ------------------------------------------------------------------- sinkhorn
// One dispatch, two block-uniform paths (interleaved by block parity):
//  even blocks: off-diagonal OT(a,b), one wave per pair (absorbed exp-domain,
//               2-lanes-per-row split + butterfly).
//  odd blocks:  diagonal OTs — one wave = (a,a) in half 0, (b,b) in half 1.
//               Symmetric C collapses alternation to z'=T(z); pair-split dot:
//               lane i reads w[16q:16q+16) only (4 b128), computes partials
//               for rows i and i^16, exchanges via one shfl_xor(16).
__global__ __launch_bounds__(256) void k_sinkhorn(
        const float* __restrict__ Z, float* __restrict__ dist) {
    __shared__ __align__(16) float smem[4][640];   // 10240 B

    int w = threadIdx.x >> 6;
    int lane = threadIdx.x & 63;
    const float CSCALE = -INV_EPS * LOG2E_F;
    const float CBIAS  = -LN32_F * LOG2E_F;

    if ((blockIdx.x & 1) == 0) {
        // ================= off-diagonal path: OT(a,b) =================
        float* sX = &smem[w][0];
        float* sY = &smem[w][256];
        float* sf = &smem[w][512];
        float* sg = &smem[w][544];
        float* su = &smem[w][576];
        float* sv = &smem[w][608];

        int b = (blockIdx.x >> 1) * 4 + w;        // 2048*4 = 8192 pairs
        int sx = b, sy = N_PAIRS + b;

        *(float4*)(&sX[lane * 4]) = ((const float4*)(Z + (size_t)sx * 256))[lane];
        *(float4*)(&sY[lane * 4]) = ((const float4*)(Z + (size_t)sy * 256))[lane];
        sg[lane & 31] = 0.0f;

        int i_r = lane & 31, jh = lane >> 5;
        int j_c = lane & 31, ih = lane >> 5;

        f2 CrowV[8], CcolV[8];
        {
            const f2* xp = (const f2*)(&sX[i_r * 8]);
            f2 x0 = xp[0], x1 = xp[1], x2 = xp[2], x3 = xp[3];
            #pragma unroll
            for (int t = 0; t < 16; ++t) {
                int j = jh * 16 + t;
                const f2* yp = (const f2*)(&sY[j * 8]);
                f2 d, s2;
                d = x0 - yp[0]; s2 = d * d;
                d = x1 - yp[1]; s2 = __builtin_elementwise_fma(d, d, s2);
                d = x2 - yp[2]; s2 = __builtin_elementwise_fma(d, d, s2);
                d = x3 - yp[3]; s2 = __builtin_elementwise_fma(d, d, s2);
                float d2 = s2.x + s2.y + 1e-12f;
                CrowV[t >> 1][t & 1] = fmaf(__builtin_amdgcn_sqrtf(d2), CSCALE, CBIAS);
            }
            const f2* yp = (const f2*)(&sY[j_c * 8]);
            f2 y0 = yp[0], y1 = yp[1], y2 = yp[2], y3 = yp[3];
            #pragma unroll
            for (int t = 0; t < 16; ++t) {
                int i = ih * 16 + t;
                const f2* qp = (const f2*)(&sX[i * 8]);
                f2 d, s2;
                d = qp[0] - y0; s2 = d * d;
                d = qp[1] - y1; s2 = __builtin_elementwise_fma(d, d, s2);
                d = qp[2] - y2; s2 = __builtin_elementwise_fma(d, d, s2);
                d = qp[3] - y3; s2 = __builtin_elementwise_fma(d, d, s2);
                float d2 = s2.x + s2.y + 1e-12f;
                CcolV[t >> 1][t & 1] = fmaf(__builtin_amdgcn_sqrtf(d2), CSCALE, CBIAS);
            }
        }

        float ft = 0.0f, gt = 0.0f;

        // Phase A: 2 log-domain iterations
        #pragma unroll 1
        for (int it = 0; it < 2; ++it) {
            {
                const float4* gp = (const float4*)(&sg[jh * 16]);
                float4 G0 = gp[0], G1 = gp[1], G2 = gp[2], G3 = gp[3];
                f2 gv[8] = {f2{G0.x, G0.y}, f2{G0.z, G0.w}, f2{G1.x, G1.y}, f2{G1.z, G1.w},
                            f2{G2.x, G2.y}, f2{G2.z, G2.w}, f2{G3.x, G3.y}, f2{G3.z, G3.w}};
                f2 val[8], m2 = f2{-1e30f, -1e30f};
                #pragma unroll
                for (int t2 = 0; t2 < 8; ++t2) {
                    val[t2] = gv[t2] + CrowV[t2];
                    m2 = __builtin_elementwise_max(m2, val[t2]);
                }
                float m = fmaxf(m2.x, m2.y);
                m = fmaxf(m, __shfl_xor(m, 32));
                f2 mm = f2{m, m};
                float s0 = 0.0f, s1 = 0.0f;
                #pragma unroll
                for (int t2 = 0; t2 < 8; ++t2) {
                    f2 e = val[t2] - mm;
                    s0 += __builtin_amdgcn_exp2f(e.x);
                    s1 += __builtin_amdgcn_exp2f(e.y);
                }
                float s = s0 + s1;
                s += __shfl_xor(s, 32);
                ft = -(m + __builtin_amdgcn_logf(s));
            }
            sf[lane & 31] = ft;
            {
                const float4* fp = (const float4*)(&sf[ih * 16]);
                float4 F0 = fp[0], F1 = fp[1], F2 = fp[2], F3 = fp[3];
                f2 fv[8] = {f2{F0.x, F0.y}, f2{F0.z, F0.w}, f2{F1.x, F1.y}, f2{F1.z, F1.w},
                            f2{F2.x, F2.y}, f2{F2.z, F2.w}, f2{F3.x, F3.y}, f2{F3.z, F3.w}};
                f2 val[8], m2 = f2{-1e30f, -1e30f};
                #pragma unroll
                for (int t2 = 0; t2 < 8; ++t2) {
                    val[t2] = fv[t2] + CcolV[t2];
                    m2 = __builtin_elementwise_max(m2, val[t2]);
                }
                float m = fmaxf(m2.x, m2.y);
                m = fmaxf(m, __shfl_xor(m, 32));
                f2 mm = f2{m, m};
                float s0 = 0.0f, s1 = 0.0f;
                #pragma unroll
                for (int t2 = 0; t2 < 8; ++t2) {
                    f2 e = val[t2] - mm;
                    s0 += __builtin_amdgcn_exp2f(e.x);
                    s1 += __builtin_amdgcn_exp2f(e.y);
                }
                float s = s0 + s1;
                s += __shfl_xor(s, 32);
                gt = -(m + __builtin_amdgcn_logf(s));
            }
            sg[lane & 31] = gt;
        }

        // Phase B: absorbed exp-domain
        f2 KR2[8], KC2[8];
        float ureg = 1.0f, vreg = 1.0f;

        auto absorb = [&]() {
            const float4* gp = (const float4*)(&sg[jh * 16]);
            float4 G0 = gp[0], G1 = gp[1], G2 = gp[2], G3 = gp[3];
            f2 gv[8] = {f2{G0.x, G0.y}, f2{G0.z, G0.w}, f2{G1.x, G1.y}, f2{G1.z, G1.w},
                        f2{G2.x, G2.y}, f2{G2.z, G2.w}, f2{G3.x, G3.y}, f2{G3.z, G3.w}};
            f2 ftv = f2{ft, ft};
            #pragma unroll
            for (int t2 = 0; t2 < 8; ++t2) {
                f2 a = (gv[t2] + CrowV[t2]) + ftv;
                KR2[t2].x = __builtin_amdgcn_exp2f(a.x);
                KR2[t2].y = __builtin_amdgcn_exp2f(a.y);
            }
            const float4* fp = (const float4*)(&sf[ih * 16]);
            float4 F0 = fp[0], F1 = fp[1], F2 = fp[2], F3 = fp[3];
            f2 fv[8] = {f2{F0.x, F0.y}, f2{F0.z, F0.w}, f2{F1.x, F1.y}, f2{F1.z, F1.w},
                        f2{F2.x, F2.y}, f2{F2.z, F2.w}, f2{F3.x, F3.y}, f2{F3.z, F3.w}};
            f2 gtv = f2{gt, gt};
            #pragma unroll
            for (int t2 = 0; t2 < 8; ++t2) {
                f2 a = (fv[t2] + CcolV[t2]) + gtv;
                KC2[t2].x = __builtin_amdgcn_exp2f(a.x);
                KC2[t2].y = __builtin_amdgcn_exp2f(a.y);
            }
            sv[lane & 31] = 1.0f;
            ureg = 1.0f;
            vreg = 1.0f;
        };

        const int blens[5] = {6, 6, 12, 12, 12};   // 48 exp iters total
        absorb();
        #pragma unroll 1
        for (int blk = 0; blk < 5; ++blk) {
            int L = blens[blk];
            #pragma unroll 2
            for (int s6 = 0; s6 < L; ++s6) {
                {
                    const float4* vp = (const float4*)(&sv[jh * 16]);
                    float4 A0 = vp[0], A1 = vp[1], A2 = vp[2], A3 = vp[3];
                    f2 acc0 = KR2[0] * f2{A0.x, A0.y};
                    f2 acc1 = KR2[1] * f2{A0.z, A0.w};
                    acc0 = __builtin_elementwise_fma(KR2[2], f2{A1.x, A1.y}, acc0);
                    acc1 = __builtin_elementwise_fma(KR2[3], f2{A1.z, A1.w}, acc1);
                    acc0 = __builtin_elementwise_fma(KR2[4], f2{A2.x, A2.y}, acc0);
                    acc1 = __builtin_elementwise_fma(KR2[5], f2{A2.z, A2.w}, acc1);
                    acc0 = __builtin_elementwise_fma(KR2[6], f2{A3.x, A3.y}, acc0);
                    acc1 = __builtin_elementwise_fma(KR2[7], f2{A3.z, A3.w}, acc1);
                    f2 a = acc0 + acc1;
                    float S = a.x + a.y;
                    S += __shfl_xor(S, 32);
                    ureg = __builtin_amdgcn_rcpf(S);
                }
                su[lane & 31] = ureg;
                {
                    const float4* up = (const float4*)(&su[ih * 16]);
                    float4 A0 = up[0], A1 = up[1], A2 = up[2], A3 = up[3];
                    f2 acc0 = KC2[0] * f2{A0.x, A0.y};
                    f2 acc1 = KC2[1] * f2{A0.z, A0.w};
                    acc0 = __builtin_elementwise_fma(KC2[2], f2{A1.x, A1.y}, acc0);
                    acc1 = __builtin_elementwise_fma(KC2[3], f2{A1.z, A1.w}, acc1);
                    acc0 = __builtin_elementwise_fma(KC2[4], f2{A2.x, A2.y}, acc0);
                    acc1 = __builtin_elementwise_fma(KC2[5], f2{A2.z, A2.w}, acc1);
                    acc0 = __builtin_elementwise_fma(KC2[6], f2{A3.x, A3.y}, acc0);
                    acc1 = __builtin_elementwise_fma(KC2[7], f2{A3.z, A3.w}, acc1);
                    f2 a = acc0 + acc1;
                    float T = a.x + a.y;
                    T += __shfl_xor(T, 32);
                    vreg = __builtin_amdgcn_rcpf(T);
                }
                sv[lane & 31] = vreg;
            }
            if (blk < 4) {
                ft += __builtin_amdgcn_logf(ureg);
                gt += __builtin_amdgcn_logf(vreg);
                sf[lane & 31] = ft;
                sg[lane & 31] = gt;
                absorb();
            }
        }
        ft += __builtin_amdgcn_logf(ureg);
        gt += __builtin_amdgcn_logf(vreg);

        float v = ft + gt;
        #pragma unroll
        for (int off = 32; off > 0; off >>= 1) v += __shfl_xor(v, off);
        if (lane == 0) {
            float cost = v * (EPS_F * LN2_F / 64.0f);
            unsafeAtomicAdd(&dist[b], cost);
        }
    } else {
        // ================= diagonal path: OT(a,a) & OT(b,b) =================
        int h = lane >> 5, i = lane & 31;
        int q = (i >> 4) & 1;                 // k-half this lane reads
        int ip = i ^ 16;                      // partner row
        int P = (blockIdx.x >> 1) * 4 + w;    // 2048*4 = 8192 pairs
        int src = h ? (N_PAIRS + P) : P;

        float* sP  = &smem[w][h * 256];       // own half's cloud
        float* swv = &smem[w][512];           // w vector [h*32 + j]
        float* spv = &smem[w][576];           // p vector at absorb

        {
            const float4* zp = (const float4*)(Z + (size_t)src * 256);
            *(float4*)(&sP[i * 8])     = zp[i * 2];
            *(float4*)(&sP[i * 8 + 4]) = zp[i * 2 + 1];
        }

        // CA: C[i][16q+t], CB: C[i^16][16q+t]  (t in [0,16))
        f2 CA[8], CB[8];
        {
            const f2* xp = (const f2*)(&sP[i * 8]);
            f2 x0 = xp[0], x1 = xp[1], x2 = xp[2], x3 = xp[3];
            const f2* bp = (const f2*)(&sP[ip * 8]);
            f2 b0 = bp[0], b1 = bp[1], b2 = bp[2], b3 = bp[3];
            #pragma unroll
            for (int t = 0; t < 16; ++t) {
                int j = q * 16 + t;
                const f2* yp = (const f2*)(&sP[j * 8]);
                f2 y0 = yp[0], y1 = yp[1], y2 = yp[2], y3 = yp[3];
                f2 d, s2;
                d = x0 - y0; s2 = d * d;
                d = x1 - y1; s2 = __builtin_elementwise_fma(d, d, s2);
                d = x2 - y2; s2 = __builtin_elementwise_fma(d, d, s2);
                d = x3 - y3; s2 = __builtin_elementwise_fma(d, d, s2);
                float d2 = s2.x + s2.y + 1e-12f;
                CA[t >> 1][t & 1] = fmaf(__builtin_amdgcn_sqrtf(d2), CSCALE, CBIAS);
                d = b0 - y0; s2 = d * d;
                d = b1 - y1; s2 = __builtin_elementwise_fma(d, d, s2);
                d = b2 - y2; s2 = __builtin_elementwise_fma(d, d, s2);
                d = b3 - y3; s2 = __builtin_elementwise_fma(d, d, s2);
                float e2 = s2.x + s2.y + 1e-12f;
                CB[t >> 1][t & 1] = fmaf(__builtin_amdgcn_sqrtf(e2), CSCALE, CBIAS);
            }
        }

        float pp = 0.0f, E = 1.0f, wcur = 1.0f, wprev = 1.0f;
        f2 KA[8], KB[8];
        #pragma unroll
        for (int t = 0; t < 8; ++t) {
            KA[t].x = __builtin_amdgcn_exp2f(CA[t].x);
            KA[t].y = __builtin_amdgcn_exp2f(CA[t].y);
            KB[t].x = __builtin_amdgcn_exp2f(CB[t].x);
            KB[t].y = __builtin_amdgcn_exp2f(CB[t].y);
        }
        swv[lane] = 1.0f;

        const int blens[9] = {4, 12, 12, 12, 12, 12, 12, 12, 12};  // 100 T-steps
        #pragma unroll 1
        for (int blk = 0; blk < 9; ++blk) {
            int L = blens[blk];
            #pragma unroll 2
            for (int s = 0; s < L; ++s) {
                const float4* wp = (const float4*)(&swv[h * 32 + q * 16]);
                float4 A0 = wp[0], A1 = wp[1], A2 = wp[2], A3 = wp[3];
                f2 aA0 = KA[0] * f2{A0.x, A0.y};
                f2 aA1 = KA[1] * f2{A0.z, A0.w};
                f2 aB0 = KB[0] * f2{A0.x, A0.y};
                f2 aB1 = KB[1] * f2{A0.z, A0.w};
                aA0 = __builtin_elementwise_fma(KA[2], f2{A1.x, A1.y}, aA0);
                aA1 = __builtin_elementwise_fma(KA[3], f2{A1.z, A1.w}, aA1);
                aB0 = __builtin_elementwise_fma(KB[2], f2{A1.x, A1.y}, aB0);
                aB1 = __builtin_elementwise_fma(KB[3], f2{A1.z, A1.w}, aB1);
                aA0 = __builtin_elementwise_fma(KA[4], f2{A2.x, A2.y}, aA0);
                aA1 = __builtin_elementwise_fma(KA[5], f2{A2.z, A2.w}, aA1);
                aB0 = __builtin_elementwise_fma(KB[4], f2{A2.x, A2.y}, aB0);
                aB1 = __builtin_elementwise_fma(KB[5], f2{A2.z, A2.w}, aB1);
                aA0 = __builtin_elementwise_fma(KA[6], f2{A3.x, A3.y}, aA0);
                aA1 = __builtin_elementwise_fma(KA[7], f2{A3.z, A3.w}, aA1);
                aB0 = __builtin_elementwise_fma(KB[6], f2{A3.x, A3.y}, aB0);
                aB1 = __builtin_elementwise_fma(KB[7], f2{A3.z, A3.w}, aB1);
                f2 aa = aA0 + aA1;
                f2 bb = aB0 + aB1;
                float pa = aa.x + aa.y;       // partial for row i   (k in q)
                float pb = bb.x + bb.y;       // partial for row i^16 (k in q)
                float other = __shfl_xor(pb, 16);   // lane i^16's row-i partial
                float S = pa + other;
                wprev = wcur;
                wcur = __builtin_amdgcn_rcpf(S) * E;
                swv[h * 32 + i] = wcur;
            }
            if (blk < 8) {
                pp += __builtin_amdgcn_logf(wcur);
                spv[lane] = pp;
                const float4* pv = (const float4*)(&spv[h * 32 + q * 16]);
                float4 P0 = pv[0], P1 = pv[1], P2 = pv[2], P3 = pv[3];
                f2 pj[8] = {f2{P0.x,P0.y}, f2{P0.z,P0.w}, f2{P1.x,P1.y}, f2{P1.z,P1.w},
                            f2{P2.x,P2.y}, f2{P2.z,P2.w}, f2{P3.x,P3.y}, f2{P3.z,P3.w}};
                #pragma unroll
                for (int t = 0; t < 8; ++t) {
                    f2 a = pj[t] + CA[t];
                    KA[t].x = __builtin_amdgcn_exp2f(a.x);
                    KA[t].y = __builtin_amdgcn_exp2f(a.y);
                    f2 c = pj[t] + CB[t];
                    KB[t].x = __builtin_amdgcn_exp2f(c.x);
                    KB[t].y = __builtin_amdgcn_exp2f(c.y);
                }
                E = __builtin_amdgcn_exp2f(-pp);
                wcur = 1.0f;
                swv[lane] = 1.0f;
            }
        }

        // z99 = pp + log2(wprev), z100 = pp + log2(wcur); cost = eps*ln2*sum/32
        float zsum = 2.0f * pp + __builtin_amdgcn_logf(wprev)
                   + __builtin_amdgcn_logf(wcur);
        #pragma unroll
        for (int off = 16; off > 0; off >>= 1) zsum += __shfl_xor(zsum, off);
        if (i == 0) {
            float cost = zsum * (EPS_F * LN2_F / 32.0f);
            unsafeAtomicAdd(&dist[P], -0.5f * cost);
        }
    }
}

// ------------------------------------------------------------------ finalize
__global__ void k_finalize(const float* __restrict__ dist,
                           const float* __restrict__ gd, float* __restrict__ out) {
    __shared__ float red[256];
    float s = 0.0f;
    for (int i = threadIdx.x; i < N_PAIRS; i += 256) {
        float g = gd[i];
        s += fabsf(dist[i] - g) / g;
    }
    red[threadIdx.x] = s;
    __syncthreads();
    for (int o = 128; o > 0; o >>= 1) {
        if (threadIdx.x < o) red[threadIdx.x] += red[threadIdx.x + o];
        __syncthreads();
    }
    if (threadIdx.x == 0) out[0] = red[0] * (1.0f / N_PAIRS);
}

// -------------------------------------------------------------------- launch
extern "C" void kernel_launch(void* const* d_in, const int* in_sizes, int n_in,
                              void* d_out, int out_size, void* d_ws, size_t ws_size,
                              hipStream_t stream) {
    const float* x    = (const float*)d_in[0];   // [50000,128]
    const float* W    = (const float*)d_in[1];   // [128,256]
    const int*   eidx = (const int*)d_in[2];     // [2,800000]
    const int*   pair = (const int*)d_in[3];     // [2,8192] flat = 16384 slots
    const float* gd   = (const float*)d_in[4];   // [8192]

    char* ws = (char*)d_ws;
    size_t off = 0;
    int*   cnt    = (int*)  (ws + off); off += (size_t)N_NODES * 4;
    int*   flags  = (int*)  (ws + off); off += (size_t)N_NODES * 4;
    float* dist   = (float*)(ws + off); off += (size_t)N_PAIRS * 4;
    size_t zero_bytes = off;                     // cnt+flags+dist contiguous
    int*   bucket = (int*)  (ws + off); off += (size_t)N_NODES * CAP * 4; // 12.8 MB
    float* Z      = (float*)(ws + off); off += (size_t)N_SLOTS * 256 * 4; // 16.8 MB

    hipMemsetAsync(d_ws, 0, zero_bytes, stream);
    k_mark    <<<(N_SLOTS + 255) / 256, 256, 0, stream>>>(pair, flags);
    k_scatter <<<N_EDGES / 256, 256, 0, stream>>>(eidx, flags, cnt, bucket);
    k_gemm    <<<N_SLOTS / 16, 256, 0, stream>>>(pair, x, cnt, bucket, W, Z);
    k_sinkhorn<<<4096, 256, 0, stream>>>(Z, dist);
    k_finalize<<<1, 256, 0, stream>>>(dist, gd, (float*)d_out);
}

// Round 8
// 252.014 us; speedup vs baseline: 3.5346x; 1.0314x over previous
//
#include <hip/hip_runtime.h>

#define N_NODES 50000
#define N_EDGES 800000
#define N_PAIRS 8192
#define N_SLOTS (2 * N_PAIRS)
#define CAP     64          // per-node bucket capacity; P(deg>63)~5e-19

// Sinkhorn constants (log2 domain):
//   C2 = -(C/eps + ln32)*log2e ; potentials kept in /(eps*ln2) units
#define INV_EPS   20.0f
#define LOG2E_F   1.4426950408889634f
#define LN2_F     0.6931471805599453f
#define LN32_F    3.4657359027997265f
#define EPS_F     0.05f

typedef float f2 __attribute__((ext_vector_type(2)));

// ---------------------------------------------------------------- mark needed
__global__ void k_mark(const int* __restrict__ pairs, int* __restrict__ flags) {
    int t = blockIdx.x * 256 + threadIdx.x;
    if (t < N_SLOTS) flags[pairs[t]] = 1;
}

// ---------------------------------------- scatter into fixed-cap buckets
__global__ __launch_bounds__(256) void k_scatter(
        const int* __restrict__ eidx, const int* __restrict__ flags,
        int* __restrict__ cnt, int* __restrict__ bucket) {
    int t = blockIdx.x * 256 + threadIdx.x;   // exact grid: 800000/256
    int dst = eidx[N_EDGES + t];
    if (!flags[dst]) return;
    int pos = atomicAdd(&cnt[dst], 1);
    if (pos < CAP) bucket[dst * CAP + pos] = eidx[t];
}

// ------------------------------------ fused gather + GEMM + relu
__global__ __launch_bounds__(256) void k_gemm(
        const int* __restrict__ pairs, const float* __restrict__ x,
        const int* __restrict__ cnt, const int* __restrict__ bucket,
        const float* __restrict__ W, float* __restrict__ Z) {
    __shared__ __align__(16) float Us[16 * 128];
    int sbase = blockIdx.x * 16;
    int t = threadIdx.x;
    int wave = t >> 6, lane = t & 63;

    #pragma unroll
    for (int rr = 0; rr < 4; ++rr) {
        int r = wave * 4 + rr;
        int node = pairs[sbase + r];
        int n = cnt[node];
        int m = (n < CAP) ? n : CAP;
        const int* bk = bucket + node * CAP;
        float ax = 0.0f, ay = 0.0f;
        int k = 0;
        for (; k + 4 <= m; k += 4) {
            int s0 = bk[k], s1 = bk[k + 1], s2 = bk[k + 2], s3 = bk[k + 3];
            float2 v0 = *(const float2*)(x + (size_t)s0 * 128 + lane * 2);
            float2 v1 = *(const float2*)(x + (size_t)s1 * 128 + lane * 2);
            float2 v2 = *(const float2*)(x + (size_t)s2 * 128 + lane * 2);
            float2 v3 = *(const float2*)(x + (size_t)s3 * 128 + lane * 2);
            ax += (v0.x + v1.x) + (v2.x + v3.x);
            ay += (v0.y + v1.y) + (v2.y + v3.y);
        }
        for (; k < m; ++k) {
            int s0 = bk[k];
            float2 v0 = *(const float2*)(x + (size_t)s0 * 128 + lane * 2);
            ax += v0.x;
            ay += v0.y;
        }
        float rdeg = 1.0f / fmaxf((float)n, 1.0f);
        float2 xv = *(const float2*)(x + (size_t)node * 128 + lane * 2);
        float2 o;
        o.x = fmaf(ax, rdeg, xv.x);
        o.y = fmaf(ay, rdeg, xv.y);
        *(float2*)(Us + r * 128 + lane * 2) = o;
    }
    __syncthreads();

    int jq = t & 63;   // column quad: cols 4*jq..4*jq+3
    int rq = t >> 6;   // row quad group: rows 4*rq..4*rq+3
    float acc[4][4] = {};
    const float4* Wv = (const float4*)W;   // W[128][256]

    for (int k4 = 0; k4 < 32; ++k4) {
        float4 wv[4];
        #pragma unroll
        for (int i = 0; i < 4; ++i) wv[i] = Wv[(size_t)(k4 * 4 + i) * 64 + jq];
        #pragma unroll
        for (int r = 0; r < 4; ++r) {
            float4 uv = *(const float4*)(Us + (rq * 4 + r) * 128 + k4 * 4);
            float uk0 = uv.x, uk1 = uv.y, uk2 = uv.z, uk3 = uv.w;
            acc[r][0] = fmaf(uk0, wv[0].x, acc[r][0]);
            acc[r][1] = fmaf(uk0, wv[0].y, acc[r][1]);
            acc[r][2] = fmaf(uk0, wv[0].z, acc[r][2]);
            acc[r][3] = fmaf(uk0, wv[0].w, acc[r][3]);
            acc[r][0] = fmaf(uk1, wv[1].x, acc[r][0]);
            acc[r][1] = fmaf(uk1, wv[1].y, acc[r][1]);
            acc[r][2] = fmaf(uk1, wv[1].z, acc[r][2]);
            acc[r][3] = fmaf(uk1, wv[1].w, acc[r][3]);
            acc[r][0] = fmaf(uk2, wv[2].x, acc[r][0]);
            acc[r][1] = fmaf(uk2, wv[2].y, acc[r][1]);
            acc[r][2] = fmaf(uk2, wv[2].z, acc[r][2]);
            acc[r][3] = fmaf(uk2, wv[2].w, acc[r][3]);
            acc[r][0] = fmaf(uk3, wv[3].x, acc[r][0]);
            acc[r][1] = fmaf(uk3, wv[3].y, acc[r][1]);
            acc[r][2] = fmaf(uk3, wv[3].z, acc[r][2]);
            acc[r][3] = fmaf(uk3, wv[3].w, acc[r][3]);
        }
    }

    #pragma unroll
    for (int r = 0; r < 4; ++r) {
        float4 o;
        o.x = fmaxf(acc[r][0], 0.0f);
        o.y = fmaxf(acc[r][1], 0.0f);
        o.z = fmaxf(acc[r][2], 0.0f);
        o.w = fmaxf(acc[r][3], 0.0f);
        *(float4*)(Z + (size_t)(sbase + rq * 4 + r) * 256 + jq * 4) = o;
    }
}

// ------------------------------------------------------------------- sinkhorn
// 128-thread blocks (2 waves) for dense CU packing; no __syncthreads at all.
//  blocks [0,4096):    diagonal OTs — one wave = (a,a) half 0 + (b,b) half 1;
//                      pair-split dot (4 b128/step) + one shfl_xor(16).
//  blocks [4096,8192): off-diagonal OT(a,b), one wave per pair (absorbed
//                      exp-domain, 2-lanes-per-row + butterfly).
// Diag is ~1.4x longer -> scheduled first to minimize makespan tail.
__global__ __launch_bounds__(128) void k_sinkhorn(
        const float* __restrict__ Z, float* __restrict__ dist) {
    __shared__ __align__(16) float smem[2][640];   // 5120 B

    int w = threadIdx.x >> 6;
    int lane = threadIdx.x & 63;
    const float CSCALE = -INV_EPS * LOG2E_F;
    const float CBIAS  = -LN32_F * LOG2E_F;

    if (blockIdx.x >= 4096) {
        // ================= off-diagonal path: OT(a,b) =================
        float* sX = &smem[w][0];
        float* sY = &smem[w][256];
        float* sf = &smem[w][512];
        float* sg = &smem[w][544];
        float* su = &smem[w][576];
        float* sv = &smem[w][608];

        int b = (blockIdx.x - 4096) * 2 + w;      // 4096*2 = 8192 pairs
        int sx = b, sy = N_PAIRS + b;

        *(float4*)(&sX[lane * 4]) = ((const float4*)(Z + (size_t)sx * 256))[lane];
        *(float4*)(&sY[lane * 4]) = ((const float4*)(Z + (size_t)sy * 256))[lane];
        sg[lane & 31] = 0.0f;

        int i_r = lane & 31, jh = lane >> 5;
        int j_c = lane & 31, ih = lane >> 5;

        f2 CrowV[8], CcolV[8];
        {
            const f2* xp = (const f2*)(&sX[i_r * 8]);
            f2 x0 = xp[0], x1 = xp[1], x2 = xp[2], x3 = xp[3];
            #pragma unroll
            for (int t = 0; t < 16; ++t) {
                int j = jh * 16 + t;
                const f2* yp = (const f2*)(&sY[j * 8]);
                f2 d, s2;
                d = x0 - yp[0]; s2 = d * d;
                d = x1 - yp[1]; s2 = __builtin_elementwise_fma(d, d, s2);
                d = x2 - yp[2]; s2 = __builtin_elementwise_fma(d, d, s2);
                d = x3 - yp[3]; s2 = __builtin_elementwise_fma(d, d, s2);
                float d2 = s2.x + s2.y + 1e-12f;
                CrowV[t >> 1][t & 1] = fmaf(__builtin_amdgcn_sqrtf(d2), CSCALE, CBIAS);
            }
            const f2* yp = (const f2*)(&sY[j_c * 8]);
            f2 y0 = yp[0], y1 = yp[1], y2 = yp[2], y3 = yp[3];
            #pragma unroll
            for (int t = 0; t < 16; ++t) {
                int i = ih * 16 + t;
                const f2* qp = (const f2*)(&sX[i * 8]);
                f2 d, s2;
                d = qp[0] - y0; s2 = d * d;
                d = qp[1] - y1; s2 = __builtin_elementwise_fma(d, d, s2);
                d = qp[2] - y2; s2 = __builtin_elementwise_fma(d, d, s2);
                d = qp[3] - y3; s2 = __builtin_elementwise_fma(d, d, s2);
                float d2 = s2.x + s2.y + 1e-12f;
                CcolV[t >> 1][t & 1] = fmaf(__builtin_amdgcn_sqrtf(d2), CSCALE, CBIAS);
            }
        }

        float ft = 0.0f, gt = 0.0f;

        // Phase A: 2 log-domain iterations
        #pragma unroll 1
        for (int it = 0; it < 2; ++it) {
            {
                const float4* gp = (const float4*)(&sg[jh * 16]);
                float4 G0 = gp[0], G1 = gp[1], G2 = gp[2], G3 = gp[3];
                f2 gv[8] = {f2{G0.x, G0.y}, f2{G0.z, G0.w}, f2{G1.x, G1.y}, f2{G1.z, G1.w},
                            f2{G2.x, G2.y}, f2{G2.z, G2.w}, f2{G3.x, G3.y}, f2{G3.z, G3.w}};
                f2 val[8], m2 = f2{-1e30f, -1e30f};
                #pragma unroll
                for (int t2 = 0; t2 < 8; ++t2) {
                    val[t2] = gv[t2] + CrowV[t2];
                    m2 = __builtin_elementwise_max(m2, val[t2]);
                }
                float m = fmaxf(m2.x, m2.y);
                m = fmaxf(m, __shfl_xor(m, 32));
                f2 mm = f2{m, m};
                float s0 = 0.0f, s1 = 0.0f;
                #pragma unroll
                for (int t2 = 0; t2 < 8; ++t2) {
                    f2 e = val[t2] - mm;
                    s0 += __builtin_amdgcn_exp2f(e.x);
                    s1 += __builtin_amdgcn_exp2f(e.y);
                }
                float s = s0 + s1;
                s += __shfl_xor(s, 32);
                ft = -(m + __builtin_amdgcn_logf(s));
            }
            sf[lane & 31] = ft;
            {
                const float4* fp = (const float4*)(&sf[ih * 16]);
                float4 F0 = fp[0], F1 = fp[1], F2 = fp[2], F3 = fp[3];
                f2 fv[8] = {f2{F0.x, F0.y}, f2{F0.z, F0.w}, f2{F1.x, F1.y}, f2{F1.z, F1.w},
                            f2{F2.x, F2.y}, f2{F2.z, F2.w}, f2{F3.x, F3.y}, f2{F3.z, F3.w}};
                f2 val[8], m2 = f2{-1e30f, -1e30f};
                #pragma unroll
                for (int t2 = 0; t2 < 8; ++t2) {
                    val[t2] = fv[t2] + CcolV[t2];
                    m2 = __builtin_elementwise_max(m2, val[t2]);
                }
                float m = fmaxf(m2.x, m2.y);
                m = fmaxf(m, __shfl_xor(m, 32));
                f2 mm = f2{m, m};
                float s0 = 0.0f, s1 = 0.0f;
                #pragma unroll
                for (int t2 = 0; t2 < 8; ++t2) {
                    f2 e = val[t2] - mm;
                    s0 += __builtin_amdgcn_exp2f(e.x);
                    s1 += __builtin_amdgcn_exp2f(e.y);
                }
                float s = s0 + s1;
                s += __shfl_xor(s, 32);
                gt = -(m + __builtin_amdgcn_logf(s));
            }
            sg[lane & 31] = gt;
        }

        // Phase B: absorbed exp-domain
        f2 KR2[8], KC2[8];
        float ureg = 1.0f, vreg = 1.0f;

        auto absorb = [&]() {
            const float4* gp = (const float4*)(&sg[jh * 16]);
            float4 G0 = gp[0], G1 = gp[1], G2 = gp[2], G3 = gp[3];
            f2 gv[8] = {f2{G0.x, G0.y}, f2{G0.z, G0.w}, f2{G1.x, G1.y}, f2{G1.z, G1.w},
                        f2{G2.x, G2.y}, f2{G2.z, G2.w}, f2{G3.x, G3.y}, f2{G3.z, G3.w}};
            f2 ftv = f2{ft, ft};
            #pragma unroll
            for (int t2 = 0; t2 < 8; ++t2) {
                f2 a = (gv[t2] + CrowV[t2]) + ftv;
                KR2[t2].x = __builtin_amdgcn_exp2f(a.x);
                KR2[t2].y = __builtin_amdgcn_exp2f(a.y);
            }
            const float4* fp = (const float4*)(&sf[ih * 16]);
            float4 F0 = fp[0], F1 = fp[1], F2 = fp[2], F3 = fp[3];
            f2 fv[8] = {f2{F0.x, F0.y}, f2{F0.z, F0.w}, f2{F1.x, F1.y}, f2{F1.z, F1.w},
                        f2{F2.x, F2.y}, f2{F2.z, F2.w}, f2{F3.x, F3.y}, f2{F3.z, F3.w}};
            f2 gtv = f2{gt, gt};
            #pragma unroll
            for (int t2 = 0; t2 < 8; ++t2) {
                f2 a = (fv[t2] + CcolV[t2]) + gtv;
                KC2[t2].x = __builtin_amdgcn_exp2f(a.x);
                KC2[t2].y = __builtin_amdgcn_exp2f(a.y);
            }
            sv[lane & 31] = 1.0f;
            ureg = 1.0f;
            vreg = 1.0f;
        };

        const int blens[5] = {6, 6, 12, 12, 12};   // 48 exp iters total
        absorb();
        #pragma unroll 1
        for (int blk = 0; blk < 5; ++blk) {
            int L = blens[blk];
            #pragma unroll 2
            for (int s6 = 0; s6 < L; ++s6) {
                {
                    const float4* vp = (const float4*)(&sv[jh * 16]);
                    float4 A0 = vp[0], A1 = vp[1], A2 = vp[2], A3 = vp[3];
                    f2 acc0 = KR2[0] * f2{A0.x, A0.y};
                    f2 acc1 = KR2[1] * f2{A0.z, A0.w};
                    acc0 = __builtin_elementwise_fma(KR2[2], f2{A1.x, A1.y}, acc0);
                    acc1 = __builtin_elementwise_fma(KR2[3], f2{A1.z, A1.w}, acc1);
                    acc0 = __builtin_elementwise_fma(KR2[4], f2{A2.x, A2.y}, acc0);
                    acc1 = __builtin_elementwise_fma(KR2[5], f2{A2.z, A2.w}, acc1);
                    acc0 = __builtin_elementwise_fma(KR2[6], f2{A3.x, A3.y}, acc0);
                    acc1 = __builtin_elementwise_fma(KR2[7], f2{A3.z, A3.w}, acc1);
                    f2 a = acc0 + acc1;
                    float S = a.x + a.y;
                    S += __shfl_xor(S, 32);
                    ureg = __builtin_amdgcn_rcpf(S);
                }
                su[lane & 31] = ureg;
                {
                    const float4* up = (const float4*)(&su[ih * 16]);
                    float4 A0 = up[0], A1 = up[1], A2 = up[2], A3 = up[3];
                    f2 acc0 = KC2[0] * f2{A0.x, A0.y};
                    f2 acc1 = KC2[1] * f2{A0.z, A0.w};
                    acc0 = __builtin_elementwise_fma(KC2[2], f2{A1.x, A1.y}, acc0);
                    acc1 = __builtin_elementwise_fma(KC2[3], f2{A1.z, A1.w}, acc1);
                    acc0 = __builtin_elementwise_fma(KC2[4], f2{A2.x, A2.y}, acc0);
                    acc1 = __builtin_elementwise_fma(KC2[5], f2{A2.z, A2.w}, acc1);
                    acc0 = __builtin_elementwise_fma(KC2[6], f2{A3.x, A3.y}, acc0);
                    acc1 = __builtin_elementwise_fma(KC2[7], f2{A3.z, A3.w}, acc1);
                    f2 a = acc0 + acc1;
                    float T = a.x + a.y;
                    T += __shfl_xor(T, 32);
                    vreg = __builtin_amdgcn_rcpf(T);
                }
                sv[lane & 31] = vreg;
            }
            if (blk < 4) {
                ft += __builtin_amdgcn_logf(ureg);
                gt += __builtin_amdgcn_logf(vreg);
                sf[lane & 31] = ft;
                sg[lane & 31] = gt;
                absorb();
            }
        }
        ft += __builtin_amdgcn_logf(ureg);
        gt += __builtin_amdgcn_logf(vreg);

        float v = ft + gt;
        #pragma unroll
        for (int off = 32; off > 0; off >>= 1) v += __shfl_xor(v, off);
        if (lane == 0) {
            float cost = v * (EPS_F * LN2_F / 64.0f);
            unsafeAtomicAdd(&dist[b], cost);
        }
    } else {
        // ================= diagonal path: OT(a,a) & OT(b,b) =================
        int h = lane >> 5, i = lane & 31;
        int q = (i >> 4) & 1;                 // k-half this lane reads
        int ip = i ^ 16;                      // partner row
        int P = blockIdx.x * 2 + w;           // 4096*2 = 8192 pairs
        int src = h ? (N_PAIRS + P) : P;

        float* sP  = &smem[w][h * 256];       // own half's cloud
        float* swv = &smem[w][512];           // w vector [h*32 + j]
        float* spv = &smem[w][576];           // p vector at absorb

        {
            const float4* zp = (const float4*)(Z + (size_t)src * 256);
            *(float4*)(&sP[i * 8])     = zp[i * 2];
            *(float4*)(&sP[i * 8 + 4]) = zp[i * 2 + 1];
        }

        // CA: C[i][16q+t], CB: C[i^16][16q+t]  (t in [0,16))
        f2 CA[8], CB[8];
        {
            const f2* xp = (const f2*)(&sP[i * 8]);
            f2 x0 = xp[0], x1 = xp[1], x2 = xp[2], x3 = xp[3];
            const f2* bp = (const f2*)(&sP[ip * 8]);
            f2 b0 = bp[0], b1 = bp[1], b2 = bp[2], b3 = bp[3];
            #pragma unroll
            for (int t = 0; t < 16; ++t) {
                int j = q * 16 + t;
                const f2* yp = (const f2*)(&sP[j * 8]);
                f2 y0 = yp[0], y1 = yp[1], y2 = yp[2], y3 = yp[3];
                f2 d, s2;
                d = x0 - y0; s2 = d * d;
                d = x1 - y1; s2 = __builtin_elementwise_fma(d, d, s2);
                d = x2 - y2; s2 = __builtin_elementwise_fma(d, d, s2);
                d = x3 - y3; s2 = __builtin_elementwise_fma(d, d, s2);
                float d2 = s2.x + s2.y + 1e-12f;
                CA[t >> 1][t & 1] = fmaf(__builtin_amdgcn_sqrtf(d2), CSCALE, CBIAS);
                d = b0 - y0; s2 = d * d;
                d = b1 - y1; s2 = __builtin_elementwise_fma(d, d, s2);
                d = b2 - y2; s2 = __builtin_elementwise_fma(d, d, s2);
                d = b3 - y3; s2 = __builtin_elementwise_fma(d, d, s2);
                float e2 = s2.x + s2.y + 1e-12f;
                CB[t >> 1][t & 1] = fmaf(__builtin_amdgcn_sqrtf(e2), CSCALE, CBIAS);
            }
        }

        float pp = 0.0f, E = 1.0f, wcur = 1.0f, wprev = 1.0f;
        f2 KA[8], KB[8];
        #pragma unroll
        for (int t = 0; t < 8; ++t) {
            KA[t].x = __builtin_amdgcn_exp2f(CA[t].x);
            KA[t].y = __builtin_amdgcn_exp2f(CA[t].y);
            KB[t].x = __builtin_amdgcn_exp2f(CB[t].x);
            KB[t].y = __builtin_amdgcn_exp2f(CB[t].y);
        }
        swv[lane] = 1.0f;

        const int blens[9] = {4, 12, 12, 12, 12, 12, 12, 12, 12};  // 100 T-steps
        #pragma unroll 1
        for (int blk = 0; blk < 9; ++blk) {
            int L = blens[blk];
            #pragma unroll 2
            for (int s = 0; s < L; ++s) {
                const float4* wp = (const float4*)(&swv[h * 32 + q * 16]);
                float4 A0 = wp[0], A1 = wp[1], A2 = wp[2], A3 = wp[3];
                f2 aA0 = KA[0] * f2{A0.x, A0.y};
                f2 aA1 = KA[1] * f2{A0.z, A0.w};
                f2 aB0 = KB[0] * f2{A0.x, A0.y};
                f2 aB1 = KB[1] * f2{A0.z, A0.w};
                aA0 = __builtin_elementwise_fma(KA[2], f2{A1.x, A1.y}, aA0);
                aA1 = __builtin_elementwise_fma(KA[3], f2{A1.z, A1.w}, aA1);
                aB0 = __builtin_elementwise_fma(KB[2], f2{A1.x, A1.y}, aB0);
                aB1 = __builtin_elementwise_fma(KB[3], f2{A1.z, A1.w}, aB1);
                aA0 = __builtin_elementwise_fma(KA[4], f2{A2.x, A2.y}, aA0);
                aA1 = __builtin_elementwise_fma(KA[5], f2{A2.z, A2.w}, aA1);
                aB0 = __builtin_elementwise_fma(KB[4], f2{A2.x, A2.y}, aB0);
                aB1 = __builtin_elementwise_fma(KB[5], f2{A2.z, A2.w}, aB1);
                aA0 = __builtin_elementwise_fma(KA[6], f2{A3.x, A3.y}, aA0);
                aA1 = __builtin_elementwise_fma(KA[7], f2{A3.z, A3.w}, aA1);
                aB0 = __builtin_elementwise_fma(KB[6], f2{A3.x, A3.y}, aB0);
                aB1 = __builtin_elementwise_fma(KB[7], f2{A3.z, A3.w}, aB1);
                f2 aa = aA0 + aA1;
                f2 bb = aB0 + aB1;
                float pa = aa.x + aa.y;       // partial for row i   (k in q)
                float pb = bb.x + bb.y;       // partial for row i^16 (k in q)
                float other = __shfl_xor(pb, 16);   // lane i^16's row-i partial
                float S = pa + other;
                wprev = wcur;
                wcur = __builtin_amdgcn_rcpf(S) * E;
                swv[h * 32 + i] = wcur;
            }
            if (blk < 8) {
                pp += __builtin_amdgcn_logf(wcur);
                spv[lane] = pp;
                const float4* pv = (const float4*)(&spv[h * 32 + q * 16]);
                float4 P0 = pv[0], P1 = pv[1], P2 = pv[2], P3 = pv[3];
                f2 pj[8] = {f2{P0.x,P0.y}, f2{P0.z,P0.w}, f2{P1.x,P1.y}, f2{P1.z,P1.w},
                            f2{P2.x,P2.y}, f2{P2.z,P2.w}, f2{P3.x,P3.y}, f2{P3.z,P3.w}};
                #pragma unroll
                for (int t = 0; t < 8; ++t) {
                    f2 a = pj[t] + CA[t];
                    KA[t].x = __builtin_amdgcn_exp2f(a.x);
                    KA[t].y = __builtin_amdgcn_exp2f(a.y);
                    f2 c = pj[t] + CB[t];
                    KB[t].x = __builtin_amdgcn_exp2f(c.x);
                    KB[t].y = __builtin_amdgcn_exp2f(c.y);
                }
                E = __builtin_amdgcn_exp2f(-pp);
                wcur = 1.0f;
                swv[lane] = 1.0f;
            }
        }

        // z99 = pp + log2(wprev), z100 = pp + log2(wcur); cost = eps*ln2*sum/32
        float zsum = 2.0f * pp + __builtin_amdgcn_logf(wprev)
                   + __builtin_amdgcn_logf(wcur);
        #pragma unroll
        for (int off = 16; off > 0; off >>= 1) zsum += __shfl_xor(zsum, off);
        if (i == 0) {
            float cost = zsum * (EPS_F * LN2_F / 32.0f);
            unsafeAtomicAdd(&dist[P], -0.5f * cost);
        }
    }
}

// ------------------------------------------------------------------ finalize
__global__ void k_finalize(const float* __restrict__ dist,
                           const float* __restrict__ gd, float* __restrict__ out) {
    __shared__ float red[256];
    float s = 0.0f;
    for (int i = threadIdx.x; i < N_PAIRS; i += 256) {
        float g = gd[i];
        s += fabsf(dist[i] - g) / g;
    }
    red[threadIdx.x] = s;
    __syncthreads();
    for (int o = 128; o > 0; o >>= 1) {
        if (threadIdx.x < o) red[threadIdx.x] += red[threadIdx.x + o];
        __syncthreads();
    }
    if (threadIdx.x == 0) out[0] = red[0] * (1.0f / N_PAIRS);
}

// -------------------------------------------------------------------- launch
extern "C" void kernel_launch(void* const* d_in, const int* in_sizes, int n_in,
                              void* d_out, int out_size, void* d_ws, size_t ws_size,
                              hipStream_t stream) {
    const float* x    = (const float*)d_in[0];   // [50000,128]
    const float* W    = (const float*)d_in[1];   // [128,256]
    const int*   eidx = (const int*)d_in[2];     // [2,800000]
    const int*   pair = (const int*)d_in[3];     // [2,8192] flat = 16384 slots
    const float* gd   = (const float*)d_in[4];   // [8192]

    char* ws = (char*)d_ws;
    size_t off = 0;
    int*   cnt    = (int*)  (ws + off); off += (size_t)N_NODES * 4;
    int*   flags  = (int*)  (ws + off); off += (size_t)N_NODES * 4;
    float* dist   = (float*)(ws + off); off += (size_t)N_PAIRS * 4;
    size_t zero_bytes = off;                     // cnt+flags+dist contiguous
    int*   bucket = (int*)  (ws + off); off += (size_t)N_NODES * CAP * 4; // 12.8 MB
    float* Z      = (float*)(ws + off); off += (size_t)N_SLOTS * 256 * 4; // 16.8 MB

    hipMemsetAsync(d_ws, 0, zero_bytes, stream);
    k_mark    <<<(N_SLOTS + 255) / 256, 256, 0, stream>>>(pair, flags);
    k_scatter <<<N_EDGES / 256, 256, 0, stream>>>(eidx, flags, cnt, bucket);
    k_gemm    <<<N_SLOTS / 16, 256, 0, stream>>>(pair, x, cnt, bucket, W, Z);
    k_sinkhorn<<<8192, 128, 0, stream>>>(Z, dist);
    k_finalize<<<1, 256, 0, stream>>>(dist, gd, (float*)d_out);
}